// Round 4
// baseline (21577.225 us; speedup 1.0000x reference)
//
#include <hip/hip_runtime.h>
#include <hip/hip_cooperative_groups.h>
#include <hip/hip_bf16.h>

namespace cg = cooperative_groups;

#define DEV __device__ __forceinline__

constexpr int B = 64, S = 128, T = 32, H = 1024, V = 32000;
constexpr int H4 = 4096;          // 4*H
constexpr int KX = 3072;          // [emb | ctx | h]
constexpr int NBL = V / 64;       // 500 logits tiles
constexpr int NBLK = 512;         // persistent grid size

using f32x4   = __attribute__((ext_vector_type(4))) float;
using short8v = __attribute__((ext_vector_type(8))) short;

DEV unsigned short f2bf(float x) {
  union { __hip_bfloat16 b; unsigned short u; } v;
  v.b = __float2bfloat16(x);
  return v.u;
}
DEV float fast_sig(float x) { return 1.0f / (1.0f + __expf(-x)); }
DEV float fast_tanh(float x) {
  float e = __expf(2.0f * x);
  return 1.0f - 2.0f / (e + 1.0f);
}

DEV void gload16(const void* g, void* l) {
  __builtin_amdgcn_global_load_lds(
      (const __attribute__((address_space(1))) void*)g,
      (__attribute__((address_space(3))) void*)l, 16, 0, 0);
}

// ---------------- LDS ----------------
struct GemmSm {
  unsigned short As[3][4096];
  unsigned short Bs[3][4096];
  float Pm[4][64];
  float Pl[4][64];
};
struct AttnSm { float qw[H]; float vw[H]; float sc[S]; float al[S]; };
struct LogZSm { float rm[256]; float rl[256]; };
union StepSm { GemmSm g; AttnSm a; LogZSm z; };

// ============ pipelined bf16 GEMM body (M=64, Ntile=64, BK=64) ============
// verified layout: lane l's 16B at l*16 -> frag row=mb*16+(l&15), k=ks*32+(l>>4)*8
template<bool PARTIALS>
DEV void gemm_body2(GemmSm& sm,
                    const unsigned short* __restrict__ A, int lda,
                    const unsigned short* __restrict__ W, int ldw,
                    int K, int n0,
                    float* __restrict__ C, size_t ldc,
                    const float* __restrict__ bias,
                    float* __restrict__ pm, float* __restrict__ pl, int pmb)
{
  const int tid = threadIdx.x;
  const int l   = tid & 63;
  const int w   = tid >> 6;

  f32x4 acc0 = {0,0,0,0}, acc1 = {0,0,0,0}, acc2 = {0,0,0,0}, acc3 = {0,0,0,0};

  const int rA = l & 15;
  const int kq = (l >> 4) << 3;

  auto stage = [&](int k0, int buf) {
    #pragma unroll
    for (int i = 0; i < 4; ++i) {
      const int c    = (w << 2) | i;
      const int side = c >> 3;
      const int ks   = (c >> 2) & 1;
      const int mb   = c & 3;
      const int kk   = k0 + ks * 32 + kq;
      const int row  = mb * 16 + rA;
      const unsigned short* src = side
        ? W + (size_t)(n0 + row) * ldw + kk
        : A + (size_t)row * lda + kk;
      unsigned short* dst = (side ? sm.Bs[buf] : sm.As[buf]) + ks * 2048 + mb * 512;
      gload16(src, dst);
    }
  };

  const int nk = K >> 6;
  stage(0, 0);
  if (nk > 1) stage(64, 1);
  for (int kt = 0; kt < nk; ++kt) {
    const int buf = kt % 3;
    if (kt + 2 < nk) {
      stage((kt + 2) << 6, (kt + 2) % 3);
      asm volatile("s_waitcnt vmcnt(8)" ::: "memory");
    } else if (kt + 1 < nk) {
      asm volatile("s_waitcnt vmcnt(4)" ::: "memory");
    } else {
      asm volatile("s_waitcnt vmcnt(0)" ::: "memory");
    }
    __builtin_amdgcn_s_barrier();
    asm volatile("" ::: "memory");
    const unsigned short* __restrict__ asb = sm.As[buf];
    const unsigned short* __restrict__ bsb = sm.Bs[buf];
    #pragma unroll
    for (int ks = 0; ks < 2; ++ks) {
      short8v bf = *(const short8v*)&bsb[ks * 2048 + (w << 9) + (l << 3)];
      acc0 = __builtin_amdgcn_mfma_f32_16x16x32_bf16(*(const short8v*)&asb[ks * 2048 + 0 * 512 + (l << 3)], bf, acc0, 0, 0, 0);
      acc1 = __builtin_amdgcn_mfma_f32_16x16x32_bf16(*(const short8v*)&asb[ks * 2048 + 1 * 512 + (l << 3)], bf, acc1, 0, 0, 0);
      acc2 = __builtin_amdgcn_mfma_f32_16x16x32_bf16(*(const short8v*)&asb[ks * 2048 + 2 * 512 + (l << 3)], bf, acc2, 0, 0, 0);
      acc3 = __builtin_amdgcn_mfma_f32_16x16x32_bf16(*(const short8v*)&asb[ks * 2048 + 3 * 512 + (l << 3)], bf, acc3, 0, 0, 0);
    }
    asm volatile("" ::: "memory");
    __builtin_amdgcn_s_barrier();
  }

  const int col = n0 + (w << 4) + (l & 15);
  const float bv = bias ? bias[col] : 0.0f;
  f32x4 accs[4] = {acc0, acc1, acc2, acc3};
  float vals[4][4];
  #pragma unroll
  for (int mb = 0; mb < 4; ++mb) {
    #pragma unroll
    for (int r = 0; r < 4; ++r) {
      int row = (mb << 4) + ((l >> 4) << 2) + r;
      float v = accs[mb][r] + bv;
      vals[mb][r] = v;
      C[(size_t)row * ldc + col] = v;
    }
  }

  if (PARTIALS) {
    #pragma unroll
    for (int mb = 0; mb < 4; ++mb) {
      #pragma unroll
      for (int r = 0; r < 4; ++r) {
        float v = vals[mb][r];
        float m = v;
        #pragma unroll
        for (int d = 1; d < 16; d <<= 1) m = fmaxf(m, __shfl_xor(m, d));
        float e = __expf(v - m);
        #pragma unroll
        for (int d = 1; d < 16; d <<= 1) e += __shfl_xor(e, d);
        if ((l & 15) == 0) {
          int row = (mb << 4) + ((l >> 4) << 2) + r;
          sm.Pm[w][row] = m;
          sm.Pl[w][row] = e;
        }
      }
    }
    __syncthreads();
    if (tid < 64) {
      float M = sm.Pm[0][tid];
      M = fmaxf(M, sm.Pm[1][tid]); M = fmaxf(M, sm.Pm[2][tid]); M = fmaxf(M, sm.Pm[3][tid]);
      float L = sm.Pl[0][tid] * __expf(sm.Pm[0][tid] - M)
              + sm.Pl[1][tid] * __expf(sm.Pm[1][tid] - M)
              + sm.Pl[2][tid] * __expf(sm.Pm[2][tid] - M)
              + sm.Pl[3][tid] * __expf(sm.Pm[3][tid] - M);
      pm[(size_t)pmb * 64 + tid] = M;
      pl[(size_t)pmb * 64 + tid] = L;
    }
    __syncthreads();
  }
}

// ---------------- persistent-kernel args ----------------
struct Args {
  // inputs
  const float *enc, *emb, *b1, *b2, *Vw, *Vb, *b_ih, *b_hh, *outb, *br1b, *br2b;
  const float *outW, *W_ih, *W_hh, *W1, *W2, *br1W, *br2W, *eh, *ec;
  const int* tok;
  // ws (bf16 weights + state)
  unsigned short *outWb, *wihb, *whhb, *w1b, *W2b, *br1Wb, *br2Wb;
  unsigned short *enc0b, *ehb, *ecb, *hbf, *xbufb;
  float *keys, *cbuf0, *cbuf1, *qW1v, *gpart, *pmv, *plv, *logZ;
  // outputs
  float *out_lp, *out_h, *out_c, *out_at;
};

DEV void cvt_range(const float* __restrict__ src, unsigned short* __restrict__ dst,
                   int n, int gtid, int gstride) {
  for (int i = gtid * 8; i < n; i += gstride * 8) {
    float4 a = *(const float4*)(src + i);
    float4 c = *(const float4*)(src + i + 4);
    ushort4 u1, u2;
    u1.x = f2bf(a.x); u1.y = f2bf(a.y); u1.z = f2bf(a.z); u1.w = f2bf(a.w);
    u2.x = f2bf(c.x); u2.y = f2bf(c.y); u2.z = f2bf(c.z); u2.w = f2bf(c.w);
    *(ushort4*)(dst + i)     = u1;
    *(ushort4*)(dst + i + 4) = u2;
  }
}

// normalize one 4096-elem unit of lp(t')
DEV void norm_apply(int j, float* __restrict__ lp_base, const float* __restrict__ logZ, int tid) {
  #pragma unroll
  for (int q = 0; q < 4; ++q) {
    size_t e = (size_t)j * 4096 + q * 1024 + tid * 4;
    int b = (int)(e / 32000);
    int r = (int)(e - (size_t)b * 32000);
    float4* p = (float4*)(lp_base + (size_t)b * T * V + r);
    float z = logZ[b];
    float4 v = *p;
    v.x -= z; v.y -= z; v.z -= z; v.w -= z;
    *p = v;
  }
}

DEV void logz_fn(LogZSm& z, const Args& a, int b, float* dst) {
  const int tid = threadIdx.x;
  float m1 = a.pmv[(size_t)tid * 64 + b];
  float l1 = a.plv[(size_t)tid * 64 + b];
  int j2 = tid + 256;
  if (j2 < NBL) {
    float m2 = a.pmv[(size_t)j2 * 64 + b], l2 = a.plv[(size_t)j2 * 64 + b];
    float M = fmaxf(m1, m2);
    l1 = l1 * __expf(m1 - M) + l2 * __expf(m2 - M);
    m1 = M;
  }
  z.rm[tid] = m1; z.rl[tid] = l1;
  __syncthreads();
  for (int off = 128; off > 0; off >>= 1) {
    if (tid < off) {
      float ma = z.rm[tid], mb2 = z.rm[tid + off];
      float M = fmaxf(ma, mb2);
      z.rl[tid] = z.rl[tid] * __expf(ma - M) + z.rl[tid + off] * __expf(mb2 - M);
      z.rm[tid] = M;
    }
    __syncthreads();
  }
  if (tid == 0) dst[b] = z.rm[0] + __logf(z.rl[0]);
  __syncthreads();
}

// fused scores+softmax+ctx+xbuf, one block per batch b
DEV void attn_fused(AttnSm& s, const Args& a, int b, int t) {
  const int tid = threadIdx.x;
  #pragma unroll
  for (int i = 0; i < 4; ++i) {
    int idx = tid + i * 256;
    s.qw[idx] = a.qW1v[b * H + idx];   // b1 already added by qW1 GEMM bias
    s.vw[idx] = a.Vw[idx];
  }
  __syncthreads();
  const int w = tid >> 6, lane = tid & 63;
  for (int si = 0; si < 32; ++si) {
    int sg = w * 32 + si;
    const float* kp = a.keys + (size_t)sg * H;
    float p = 0.0f;
    #pragma unroll
    for (int u = 0; u < 16; ++u) {
      int h = lane + (u << 6);
      p += s.vw[h] * fast_tanh(s.qw[h] + kp[h]);
    }
    #pragma unroll
    for (int d = 1; d < 64; d <<= 1) p += __shfl_xor(p, d);
    if (lane == 0) s.sc[sg] = p + a.Vb[0];
  }
  __syncthreads();
  if (tid < 64) {
    float a0 = s.sc[tid], a1 = s.sc[tid + 64];
    float m = fmaxf(a0, a1);
    #pragma unroll
    for (int d = 1; d < 64; d <<= 1) m = fmaxf(m, __shfl_xor(m, d));
    float e0 = __expf(a0 - m), e1 = __expf(a1 - m);
    float sum = e0 + e1;
    #pragma unroll
    for (int d = 1; d < 64; d <<= 1) sum += __shfl_xor(sum, d);
    float v0 = e0 / sum, v1 = e1 / sum;
    s.al[tid] = v0; s.al[tid + 64] = v1;
    a.out_at[((size_t)t * B + b) * S + tid]      = v0;
    a.out_at[((size_t)t * B + b) * S + tid + 64] = v1;
  }
  __syncthreads();
  float4 acc = {0, 0, 0, 0};
  const float* ep = a.enc + (size_t)b * S * H + tid * 4;
  for (int sx = 0; sx < S; ++sx) {
    float4 e4 = *(const float4*)(ep + (size_t)sx * H);
    float av = s.al[sx];
    acc.x += av * e4.x; acc.y += av * e4.y; acc.z += av * e4.z; acc.w += av * e4.w;
  }
  int token = a.tok[b * T + t];
  float4 em = *(const float4*)(a.emb + (size_t)token * H + tid * 4);
  ushort4 ue, uc;
  ue.x = f2bf(em.x);  ue.y = f2bf(em.y);  ue.z = f2bf(em.z);  ue.w = f2bf(em.w);
  uc.x = f2bf(acc.x); uc.y = f2bf(acc.y); uc.z = f2bf(acc.z); uc.w = f2bf(acc.w);
  unsigned short* xb = a.xbufb + (size_t)b * KX;
  *(ushort4*)(xb + tid * 4)         = ue;
  *(ushort4*)(xb + H + tid * 4)     = uc;
  *(ushort4*)(xb + 2 * H + tid * 4) = *(const ushort4*)(a.hbf + b * H + tid * 4);
}

DEV void cell_fn(const Args& a, int bx, int t) {
  const int tid = threadIdx.x;
  const int idx = bx * 256 + tid;
  const int b = idx >> 10, h = idx & 1023;
  const float* cp = (t & 1) ? a.cbuf1 : a.cbuf0;
  float* cn = (t & 1) ? a.cbuf0 : a.cbuf1;
  float gi = a.b_ih[h]         + a.b_hh[h];
  float gf = a.b_ih[H + h]     + a.b_hh[H + h];
  float gg = a.b_ih[2 * H + h] + a.b_hh[2 * H + h];
  float go = a.b_ih[3 * H + h] + a.b_hh[3 * H + h];
  #pragma unroll
  for (int p = 0; p < 6; ++p) {
    const float* g = a.gpart + (size_t)p * B * H4 + (size_t)b * H4;
    gi += g[h]; gf += g[H + h]; gg += g[2 * H + h]; go += g[3 * H + h];
  }
  float c = fast_sig(gf) * cp[idx] + fast_sig(gi) * fast_tanh(gg);
  float hv = fast_sig(go) * fast_tanh(c);
  cn[idx] = c;
  a.hbf[idx] = f2bf(hv);
  if (t == T - 1) { a.out_h[idx] = hv; a.out_c[idx] = c; }
}

// ============================ the persistent kernel ========================
__global__ __launch_bounds__(256, 2) void k_persist(Args a) {
  cg::grid_group grid = cg::this_grid();
  __shared__ StepSm sm;
  const int bx = blockIdx.x;
  const int tid = threadIdx.x;
  const int gtid = bx * 256 + tid;
  const int gstride = NBLK * 256;

  auto gsync = [&]() { __threadfence(); grid.sync(); };

  // phase 0: all weight/activation conversions
  cvt_range(a.outW, a.outWb, V * H, gtid, gstride);
  cvt_range(a.W_ih, a.wihb, H4 * 2 * H, gtid, gstride);
  cvt_range(a.W_hh, a.whhb, H4 * H, gtid, gstride);
  cvt_range(a.W1,   a.w1b,   H * H, gtid, gstride);
  cvt_range(a.W2,   a.W2b,   H * H, gtid, gstride);
  cvt_range(a.br1W, a.br1Wb, H * H, gtid, gstride);
  cvt_range(a.br2W, a.br2Wb, H * H, gtid, gstride);
  cvt_range(a.enc,  a.enc0b, S * H, gtid, gstride);
  cvt_range(a.eh,   a.ehb,   B * H, gtid, gstride);
  cvt_range(a.ec,   a.ecb,   B * H, gtid, gstride);
  gsync();

  // phase 0.5: prep GEMMs (keys rows 0-63 / 64-127, h0 bridge, c0 bridge)
  if (bx < 16)
    gemm_body2<false>(sm.g, a.enc0b, H, a.W2b, H, H, bx * 64, a.keys, H, a.b2, nullptr, nullptr, 0);
  else if (bx < 32)
    gemm_body2<false>(sm.g, a.enc0b + 64 * H, H, a.W2b, H, H, (bx - 16) * 64, a.keys + 64 * H, H, a.b2, nullptr, nullptr, 0);
  else if (bx < 48)
    gemm_body2<false>(sm.g, a.ehb, H, a.br1Wb, H, H, (bx - 32) * 64, a.gpart, H, a.br1b, nullptr, nullptr, 0);
  else if (bx < 64)
    gemm_body2<false>(sm.g, a.ecb, H, a.br2Wb, H, H, (bx - 48) * 64, a.cbuf0, H, a.br2b, nullptr, nullptr, 0);
  gsync();

  // phase 0.75: hbf = bf16(h0)
  if (bx < 64) {
    int i4 = (bx * 256 + tid) * 4;
    float4 v = *(const float4*)(a.gpart + i4);
    ushort4 u;
    u.x = f2bf(v.x); u.y = f2bf(v.y); u.z = f2bf(v.z); u.w = f2bf(v.w);
    *(ushort4*)(a.hbf + i4) = u;
  }
  gsync();

  for (int t = 0; t < T; ++t) {
    // P1: qW1 (16) + logits(t-1) tiles 0..495
    if (bx < 16) {
      gemm_body2<false>(sm.g, a.hbf, H, a.w1b, H, H, bx * 64, a.qW1v, H, a.b1, nullptr, nullptr, 0);
    } else if (t > 0) {
      int tile = bx - 16;  // 0..495
      gemm_body2<true>(sm.g, a.hbf, H, a.outWb, H, H, tile * 64,
                       a.out_lp + (size_t)(t - 1) * V, (size_t)T * V, a.outb, a.pmv, a.plv, tile);
    }
    gsync();
    // P2: fused attn (64) + logits tiles 496..499 + norm(t-2)
    if (bx < 64) {
      attn_fused(sm.a, a, bx, t);
    } else if (bx < 68) {
      if (t > 0) {
        int tile = 496 + (bx - 64);
        gemm_body2<true>(sm.g, a.hbf, H, a.outWb, H, H, tile * 64,
                         a.out_lp + (size_t)(t - 1) * V, (size_t)T * V, a.outb, a.pmv, a.plv, tile);
      }
    } else if (t >= 2) {
      for (int j = bx - 68; j < 500; j += NBLK - 68)
        norm_apply(j, a.out_lp + (size_t)(t - 2) * V, a.logZ + ((t - 2) & 1) * B, tid);
    }
    gsync();
    // P3: gates split-K x6 (384) + logZ(t-1) (64)
    if (bx < 384) {
      const int kc = bx >> 6, nb = bx & 63;
      const unsigned short* A; const unsigned short* W; int ldw;
      if (kc < 4) { A = a.xbufb + kc * 512; W = a.wihb + kc * 512; ldw = 2 * H; }
      else        { A = a.xbufb + 2048 + (kc - 4) * 512; W = a.whhb + (kc - 4) * 512; ldw = H; }
      gemm_body2<false>(sm.g, A, KX, W, ldw, 512, nb * 64,
                        a.gpart + (size_t)kc * B * H4, (size_t)H4, nullptr, nullptr, nullptr, 0);
    } else if (bx < 448 && t > 0) {
      logz_fn(sm.z, a, bx - 384, a.logZ + ((t - 1) & 1) * B);
    }
    gsync();
    // P4: cell
    if (bx < 256) cell_fn(a, bx, t);
    gsync();
  }

  // finale: logits(T-1)
  if (bx < NBL)
    gemm_body2<true>(sm.g, a.hbf, H, a.outWb, H, H, bx * 64,
                     a.out_lp + (size_t)(T - 1) * V, (size_t)T * V, a.outb, a.pmv, a.plv, bx);
  gsync();
  if (bx < 64)
    logz_fn(sm.z, a, bx, a.logZ + ((T - 1) & 1) * B);
  else
    for (int j = bx - 64; j < 500; j += NBLK - 64)
      norm_apply(j, a.out_lp + (size_t)(T - 2) * V, a.logZ + ((T - 2) & 1) * B, tid);
  gsync();
  for (int j = bx; j < 500; j += NBLK)
    norm_apply(j, a.out_lp + (size_t)(T - 1) * V, a.logZ + ((T - 1) & 1) * B, tid);
}

// ================= legacy fallback kernels (R1-proven) =====================
__global__ __launch_bounds__(256) void k_f32_to_bf16(
    const float* __restrict__ src, unsigned short* __restrict__ dst, int n) {
  int i0 = (blockIdx.x * 256 + threadIdx.x) * 8;
  int stride = gridDim.x * 256 * 8;
  for (int i = i0; i < n; i += stride) {
    float4 a = *(const float4*)(src + i);
    float4 c = *(const float4*)(src + i + 4);
    ushort4 u1, u2;
    u1.x = f2bf(a.x); u1.y = f2bf(a.y); u1.z = f2bf(a.z); u1.w = f2bf(a.w);
    u2.x = f2bf(c.x); u2.y = f2bf(c.y); u2.z = f2bf(c.z); u2.w = f2bf(c.w);
    *(ushort4*)(dst + i)     = u1;
    *(ushort4*)(dst + i + 4) = u2;
  }
}

__global__ __launch_bounds__(256) void gemm64_mfma(
    const float* __restrict__ A, int lda,
    const void* __restrict__ Wa, int ldwa,
    const void* __restrict__ Wb, int ldwb, int ksplit,
    const float* __restrict__ bias1, const float* __restrict__ bias2,
    float* __restrict__ C, size_t ldc,
    int K, int wbf16,
    float* __restrict__ pm, float* __restrict__ pl)
{
  __shared__ unsigned short As[2048];
  __shared__ unsigned short Bs[2048];
  __shared__ float Pm[4][64];
  __shared__ float Pl[4][64];

  const int tid  = threadIdx.x;
  const int lane = tid & 63;
  const int w    = tid >> 6;
  const int n0   = blockIdx.x * 64;

  f32x4 acc0 = {0.f,0.f,0.f,0.f}, acc1 = {0.f,0.f,0.f,0.f};
  f32x4 acc2 = {0.f,0.f,0.f,0.f}, acc3 = {0.f,0.f,0.f,0.f};

  for (int k0 = 0; k0 < K; k0 += 32) {
    #pragma unroll
    for (int ss = 0; ss < 2; ++ss) {
      int s  = tid + ss * 256;
      int r  = s >> 3;
      int kq = s & 7;
      int kL = kq * 4;
      int kg = k0 + kL;
      const float* ap = A + (size_t)r * lda + kg;
      float4 av = *(const float4*)ap;
      ushort4 au;
      au.x = f2bf(av.x); au.y = f2bf(av.y); au.z = f2bf(av.z); au.w = f2bf(av.w);
      int dst = ((r >> 4) << 9) + ((kL >> 3) << 7) + ((r & 15) << 3) + (kL & 7);
      *(ushort4*)&As[dst] = au;
      int n = n0 + r;
      ushort4 bu;
      if (wbf16) {
        const unsigned short* wpp = (kg < ksplit)
          ? (const unsigned short*)Wa + (size_t)n * ldwa + kg
          : (const unsigned short*)Wb + (size_t)n * ldwb + (kg - ksplit);
        bu = *(const ushort4*)wpp;
      } else {
        const float* wpp = (kg < ksplit)
          ? (const float*)Wa + (size_t)n * ldwa + kg
          : (const float*)Wb + (size_t)n * ldwb + (kg - ksplit);
        float4 wv = *(const float4*)wpp;
        bu.x = f2bf(wv.x); bu.y = f2bf(wv.y); bu.z = f2bf(wv.z); bu.w = f2bf(wv.w);
      }
      *(ushort4*)&Bs[dst] = bu;
    }
    __syncthreads();
    short8v bf = *(const short8v*)&Bs[(w << 9) + (lane << 3)];
    short8v a0 = *(const short8v*)&As[(0 << 9) + (lane << 3)];
    short8v a1 = *(const short8v*)&As[(1 << 9) + (lane << 3)];
    short8v a2 = *(const short8v*)&As[(2 << 9) + (lane << 3)];
    short8v a3 = *(const short8v*)&As[(3 << 9) + (lane << 3)];
    acc0 = __builtin_amdgcn_mfma_f32_16x16x32_bf16(a0, bf, acc0, 0, 0, 0);
    acc1 = __builtin_amdgcn_mfma_f32_16x16x32_bf16(a1, bf, acc1, 0, 0, 0);
    acc2 = __builtin_amdgcn_mfma_f32_16x16x32_bf16(a2, bf, acc2, 0, 0, 0);
    acc3 = __builtin_amdgcn_mfma_f32_16x16x32_bf16(a3, bf, acc3, 0, 0, 0);
    __syncthreads();
  }

  const int col = n0 + (w << 4) + (lane & 15);
  const float bv = (bias1 ? bias1[col] : 0.0f) + (bias2 ? bias2[col] : 0.0f);
  f32x4 accs[4] = {acc0, acc1, acc2, acc3};
  float vals[4][4];
  #pragma unroll
  for (int mb = 0; mb < 4; ++mb) {
    #pragma unroll
    for (int r = 0; r < 4; ++r) {
      int row = (mb << 4) + ((lane >> 4) << 2) + r;
      float v = accs[mb][r] + bv;
      vals[mb][r] = v;
      C[(size_t)row * ldc + col] = v;
    }
  }

  if (pm) {
    #pragma unroll
    for (int mb = 0; mb < 4; ++mb) {
      #pragma unroll
      for (int r = 0; r < 4; ++r) {
        float v = vals[mb][r];
        float m = v;
        #pragma unroll
        for (int d = 1; d < 16; d <<= 1) m = fmaxf(m, __shfl_xor(m, d));
        float e = __expf(v - m);
        #pragma unroll
        for (int d = 1; d < 16; d <<= 1) e += __shfl_xor(e, d);
        if ((lane & 15) == 0) {
          int row = (mb << 4) + ((lane >> 4) << 2) + r;
          Pm[w][row] = m;
          Pl[w][row] = e;
        }
      }
    }
    __syncthreads();
    if (tid < 64) {
      float M = Pm[0][tid];
      M = fmaxf(M, Pm[1][tid]); M = fmaxf(M, Pm[2][tid]); M = fmaxf(M, Pm[3][tid]);
      float L = Pl[0][tid] * __expf(Pm[0][tid] - M)
              + Pl[1][tid] * __expf(Pm[1][tid] - M)
              + Pl[2][tid] * __expf(Pm[2][tid] - M)
              + Pl[3][tid] * __expf(Pm[3][tid] - M);
      pm[(size_t)blockIdx.x * 64 + tid] = M;
      pl[(size_t)blockIdx.x * 64 + tid] = L;
    }
  }
}

__global__ __launch_bounds__(256) void k_scores_leg(
    const float* __restrict__ qW1, const float* __restrict__ keys,
    const float* __restrict__ Vw, const float* __restrict__ Vb,
    float* __restrict__ scores)
{
  __shared__ float qw[H];
  __shared__ float vw[H];
  const int b  = blockIdx.x >> 2;
  const int sq = blockIdx.x & 3;
  const int tid = threadIdx.x;
  #pragma unroll
  for (int i = 0; i < 4; ++i) {
    qw[tid + i * 256] = qW1[b * H + tid + i * 256];
    vw[tid + i * 256] = Vw[tid + i * 256];
  }
  __syncthreads();
  const int w = tid >> 6, lane = tid & 63;
  #pragma unroll
  for (int si = 0; si < 8; ++si) {
    int sg = sq * 32 + w * 8 + si;
    const float* kp = keys + (size_t)sg * H;
    float p = 0.0f;
    #pragma unroll
    for (int u = 0; u < 16; ++u) {
      int h = lane + (u << 6);
      p += vw[h] * fast_tanh(qw[h] + kp[h]);
    }
    #pragma unroll
    for (int d = 1; d < 64; d <<= 1) p += __shfl_xor(p, d);
    if (lane == 0) scores[b * S + sg] = p + Vb[0];
  }
}

__global__ __launch_bounds__(256) void k_attn_ctx_leg(
    const float* __restrict__ scores, const float* __restrict__ enc,
    const float* __restrict__ emb, const int* __restrict__ tok,
    const float* __restrict__ hcur, float* __restrict__ xbuf,
    float* __restrict__ attn_out, int t)
{
  __shared__ float al[S];
  __shared__ float wred[4];
  const int b   = blockIdx.x >> 2;
  const int hq  = blockIdx.x & 3;
  const int tid = threadIdx.x;

  float sv = (tid < S) ? scores[b * S + tid] : -1e30f;
  float m = sv;
  #pragma unroll
  for (int d = 1; d < 64; d <<= 1) m = fmaxf(m, __shfl_xor(m, d));
  if ((tid & 63) == 0) wred[tid >> 6] = m;
  __syncthreads();
  m = fmaxf(fmaxf(wred[0], wred[1]), fmaxf(wred[2], wred[3]));
  float e = (tid < S) ? __expf(sv - m) : 0.0f;
  float ssum = e;
  #pragma unroll
  for (int d = 1; d < 64; d <<= 1) ssum += __shfl_xor(ssum, d);
  __syncthreads();
  if ((tid & 63) == 0) wred[tid >> 6] = ssum;
  __syncthreads();
  float tot = wred[0] + wred[1] + wred[2] + wred[3];
  float a = e / tot;
  if (tid < S) {
    al[tid] = a;
    if (hq == 0) attn_out[((size_t)t * B + b) * S + tid] = a;
  }
  __syncthreads();

  const int h = hq * 256 + tid;
  float acc = 0.0f;
  const float* ep = enc + (size_t)b * S * H + h;
  #pragma unroll 4
  for (int s = 0; s < S; ++s) acc += al[s] * ep[(size_t)s * H];

  int token = tok[b * T + t];
  xbuf[b * KX + h]         = emb[(size_t)token * H + h];
  xbuf[b * KX + H + h]     = acc;
  xbuf[b * KX + 2 * H + h] = hcur[b * H + h];
}

__global__ __launch_bounds__(256) void k_cell_leg(
    const float* __restrict__ gates, const float* __restrict__ cprev,
    float* __restrict__ hnew, float* __restrict__ cnew,
    float* __restrict__ hout, float* __restrict__ cout, int last)
{
  int idx = blockIdx.x * 256 + threadIdx.x;
  int b = idx >> 10, h = idx & 1023;
  const float* g = gates + (size_t)b * H4;
  float gi = g[h], gf = g[H + h], gg = g[2 * H + h], go = g[3 * H + h];
  float c = fast_sig(gf) * cprev[idx] + fast_sig(gi) * fast_tanh(gg);
  float hv = fast_sig(go) * fast_tanh(c);
  cnew[idx] = c;
  hnew[idx] = hv;
  if (last) { hout[idx] = hv; cout[idx] = c; }
}

__global__ __launch_bounds__(256) void k_norm_leg(
    const float* __restrict__ pm, const float* __restrict__ pl,
    float* __restrict__ lp, int t)
{
  __shared__ float rm[256], rl[256];
  const int bx = blockIdx.x;
  const int b  = bx / 125;
  const int ch = bx % 125;
  const int tid = threadIdx.x;

  float m1 = pm[(size_t)tid * 64 + b];
  float l1 = pl[(size_t)tid * 64 + b];
  int nb2 = tid + 256;
  if (nb2 < NBL) {
    float m2 = pm[(size_t)nb2 * 64 + b];
    float l2 = pl[(size_t)nb2 * 64 + b];
    float M = fmaxf(m1, m2);
    l1 = l1 * __expf(m1 - M) + l2 * __expf(m2 - M);
    m1 = M;
  }
  rm[tid] = m1; rl[tid] = l1;
  __syncthreads();
  for (int off = 128; off > 0; off >>= 1) {
    if (tid < off) {
      float ma = rm[tid], mb = rm[tid + off];
      float M = fmaxf(ma, mb);
      rl[tid] = rl[tid] * __expf(ma - M) + rl[tid + off] * __expf(mb - M);
      rm[tid] = M;
    }
    __syncthreads();
  }
  float logZ = rm[0] + __logf(rl[0]);
  size_t base = ((size_t)b * T + t) * V + (size_t)ch * 256;
  lp[base + tid] -= logZ;
}

// ============================ host launcher ================================
static void run_legacy(void* const* d_in, void* d_out, void* d_ws, size_t ws_size,
                       hipStream_t stream)
{
  const float* enc  = (const float*)d_in[0];
  const float* eh   = (const float*)d_in[1];
  const float* ec   = (const float*)d_in[2];
  const int*   tok  = (const int*)d_in[4];
  const float* emb  = (const float*)d_in[5];
  const float* W1   = (const float*)d_in[6];
  const float* b1   = (const float*)d_in[7];
  const float* W2   = (const float*)d_in[8];
  const float* b2   = (const float*)d_in[9];
  const float* Vw   = (const float*)d_in[10];
  const float* Vb   = (const float*)d_in[11];
  const float* W_ih = (const float*)d_in[12];
  const float* W_hh = (const float*)d_in[13];
  const float* b_ih = (const float*)d_in[14];
  const float* b_hh = (const float*)d_in[15];
  const float* outW = (const float*)d_in[16];
  const float* outb = (const float*)d_in[17];
  const float* br1W = (const float*)d_in[18];
  const float* br1b = (const float*)d_in[19];
  const float* br2W = (const float*)d_in[20];
  const float* br2b = (const float*)d_in[21];

  float* out    = (float*)d_out;
  float* out_lp = out;
  float* out_h  = out + (size_t)B * T * V;
  float* out_c  = out_h + B * H;
  float* out_at = out_c + B * H;

  char* wp = (char*)d_ws;
  auto alloc = [&](size_t bytes) {
    char* p = wp; wp += (bytes + 255) & ~(size_t)255; return p;
  };
  float* keysL   = (float*)alloc((size_t)S * H * 4);
  float* hbuf0   = (float*)alloc((size_t)B * H * 4);
  float* hbuf1   = (float*)alloc((size_t)B * H * 4);
  float* cbuf0L  = (float*)alloc((size_t)B * H * 4);
  float* cbuf1L  = (float*)alloc((size_t)B * H * 4);
  float* qW1vL   = (float*)alloc((size_t)B * H * 4);
  float* scoresL = (float*)alloc((size_t)B * S * 4);
  float* xbuf    = (float*)alloc((size_t)B * KX * 4);
  float* gates   = (float*)alloc((size_t)B * H4 * 4);
  float* pmvL    = (float*)alloc((size_t)NBL * 64 * 4);
  float* plvL    = (float*)alloc((size_t)NBL * 64 * 4);
  unsigned short* outWbL = (unsigned short*)alloc((size_t)V * H * 2);
  size_t need_out = (size_t)(wp - (char*)d_ws);
  unsigned short* wihbL = (unsigned short*)alloc((size_t)H4 * 2 * H * 2);
  unsigned short* whhbL = (unsigned short*)alloc((size_t)H4 * H * 2);
  unsigned short* w1bL  = (unsigned short*)alloc((size_t)H * H * 2);
  size_t need_all = (size_t)(wp - (char*)d_ws);

  const bool cvtOut = ws_size >= need_out;
  const bool cvtAll = ws_size >= need_all;

  if (cvtOut) k_f32_to_bf16<<<4096, 256, 0, stream>>>(outW, outWbL, V * H);
  if (cvtAll) {
    k_f32_to_bf16<<<2048, 256, 0, stream>>>(W_ih, wihbL, H4 * 2 * H);
    k_f32_to_bf16<<<1024, 256, 0, stream>>>(W_hh, whhbL, H4 * H);
    k_f32_to_bf16<<<256, 256, 0, stream>>>(W1, w1bL, H * H);
  }

  gemm64_mfma<<<16, 256, 0, stream>>>(enc,          H, W2, H, W2, H, H, b2, nullptr, keysL,          H, H, 0, nullptr, nullptr);
  gemm64_mfma<<<16, 256, 0, stream>>>(enc + 64 * H, H, W2, H, W2, H, H, b2, nullptr, keysL + 64 * H, H, H, 0, nullptr, nullptr);
  gemm64_mfma<<<16, 256, 0, stream>>>(eh, H, br1W, H, br1W, H, H, br1b, nullptr, hbuf0, H, H, 0, nullptr, nullptr);
  gemm64_mfma<<<16, 256, 0, stream>>>(ec, H, br2W, H, br2W, H, H, br2b, nullptr, cbuf0L, H, H, 0, nullptr, nullptr);

  float* hb[2] = {hbuf0, hbuf1};
  float* cb[2] = {cbuf0L, cbuf1L};

  for (int t = 0; t < T; ++t) {
    const int cur = t & 1, nxt = cur ^ 1;
    if (cvtAll)
      gemm64_mfma<<<16, 256, 0, stream>>>(hb[cur], H, w1bL, H, w1bL, H, H, b1, nullptr, qW1vL, H, H, 1, nullptr, nullptr);
    else
      gemm64_mfma<<<16, 256, 0, stream>>>(hb[cur], H, W1, H, W1, H, H, b1, nullptr, qW1vL, H, H, 0, nullptr, nullptr);
    k_scores_leg<<<256, 256, 0, stream>>>(qW1vL, keysL, Vw, Vb, scoresL);
    k_attn_ctx_leg<<<256, 256, 0, stream>>>(scoresL, enc, emb, tok, hb[cur], xbuf, out_at, t);
    if (cvtAll)
      gemm64_mfma<<<64, 256, 0, stream>>>(xbuf, KX, wihbL, 2 * H, whhbL, H, 2 * H, b_ih, b_hh, gates, H4, KX, 1, nullptr, nullptr);
    else
      gemm64_mfma<<<64, 256, 0, stream>>>(xbuf, KX, W_ih, 2 * H, W_hh, H, 2 * H, b_ih, b_hh, gates, H4, KX, 0, nullptr, nullptr);
    k_cell_leg<<<256, 256, 0, stream>>>(gates, cb[cur], hb[nxt], cb[nxt], out_h, out_c, t == T - 1);
    if (cvtOut)
      gemm64_mfma<<<NBL, 256, 0, stream>>>(hb[nxt], H, outWbL, H, outWbL, H, H, outb, nullptr, out + (size_t)t * V, (size_t)T * V, H, 1, pmvL, plvL);
    else
      gemm64_mfma<<<NBL, 256, 0, stream>>>(hb[nxt], H, outW, H, outW, H, H, outb, nullptr, out + (size_t)t * V, (size_t)T * V, H, 0, pmvL, plvL);
    k_norm_leg<<<64 * 125, 256, 0, stream>>>(pmvL, plvL, out, t);
  }
}

extern "C" void kernel_launch(void* const* d_in, const int* in_sizes, int n_in,
                              void* d_out, int out_size, void* d_ws, size_t ws_size,
                              hipStream_t stream)
{
  (void)in_sizes; (void)n_in; (void)out_size;

  float* out = (float*)d_out;
  Args a;
  a.enc  = (const float*)d_in[0];
  a.eh   = (const float*)d_in[1];
  a.ec   = (const float*)d_in[2];
  a.tok  = (const int*)d_in[4];
  a.emb  = (const float*)d_in[5];
  a.W1   = (const float*)d_in[6];
  a.b1   = (const float*)d_in[7];
  a.W2   = (const float*)d_in[8];
  a.b2   = (const float*)d_in[9];
  a.Vw   = (const float*)d_in[10];
  a.Vb   = (const float*)d_in[11];
  a.W_ih = (const float*)d_in[12];
  a.W_hh = (const float*)d_in[13];
  a.b_ih = (const float*)d_in[14];
  a.b_hh = (const float*)d_in[15];
  a.outW = (const float*)d_in[16];
  a.outb = (const float*)d_in[17];
  a.br1W = (const float*)d_in[18];
  a.br1b = (const float*)d_in[19];
  a.br2W = (const float*)d_in[20];
  a.br2b = (const float*)d_in[21];

  a.out_lp = out;
  a.out_h  = out + (size_t)B * T * V;
  a.out_c  = a.out_h + B * H;
  a.out_at = a.out_c + B * H;

  char* wp = (char*)d_ws;
  auto alloc = [&](size_t bytes) {
    char* p = wp; wp += (bytes + 255) & ~(size_t)255; return p;
  };
  a.keys   = (float*)alloc((size_t)S * H * 4);
  a.cbuf0  = (float*)alloc((size_t)B * H * 4);
  a.cbuf1  = (float*)alloc((size_t)B * H * 4);
  a.qW1v   = (float*)alloc((size_t)B * H * 4);
  a.xbufb  = (unsigned short*)alloc((size_t)B * KX * 2);
  a.gpart  = (float*)alloc((size_t)6 * B * H4 * 4);
  a.pmv    = (float*)alloc((size_t)NBL * 64 * 4);
  a.plv    = (float*)alloc((size_t)NBL * 64 * 4);
  a.logZ   = (float*)alloc((size_t)2 * B * 4);
  a.hbf    = (unsigned short*)alloc((size_t)B * H * 2);
  a.outWb  = (unsigned short*)alloc((size_t)V * H * 2);
  a.wihb   = (unsigned short*)alloc((size_t)H4 * 2 * H * 2);
  a.whhb   = (unsigned short*)alloc((size_t)H4 * H * 2);
  a.w1b    = (unsigned short*)alloc((size_t)H * H * 2);
  a.W2b    = (unsigned short*)alloc((size_t)H * H * 2);
  a.br1Wb  = (unsigned short*)alloc((size_t)H * H * 2);
  a.br2Wb  = (unsigned short*)alloc((size_t)H * H * 2);
  a.enc0b  = (unsigned short*)alloc((size_t)S * H * 2);
  a.ehb    = (unsigned short*)alloc((size_t)B * H * 2);
  a.ecb    = (unsigned short*)alloc((size_t)B * H * 2);
  size_t need_fast = (size_t)(wp - (char*)d_ws);

  if (ws_size >= need_fast) {
    void* kargs[] = { (void*)&a };
    hipError_t err = hipLaunchCooperativeKernel(
        (const void*)k_persist, dim3(NBLK), dim3(256), kargs, 0, stream);
    if (err == hipSuccess) return;
    // cooperative launch unavailable -> fall through to legacy
  }
  run_legacy(d_in, d_out, d_ws, ws_size, stream);
}

// Round 5
// 10853.942 us; speedup vs baseline: 1.9880x; 1.9880x over previous
//
#include <hip/hip_runtime.h>
#include <hip/hip_bf16.h>

#define DEV __device__ __forceinline__

constexpr int B = 64, S = 128, T = 32, H = 1024, V = 32000;
constexpr int H4 = 4096;          // 4*H
constexpr int KX = 3072;          // [emb | ctx | h]
constexpr int NBL = V / 64;       // 500 logits tiles
constexpr int NBLK = 512;         // persistent grid size

using f32x4   = __attribute__((ext_vector_type(4))) float;
using short8v = __attribute__((ext_vector_type(8))) short;

DEV unsigned short f2bf(float x) {
  union { __hip_bfloat16 b; unsigned short u; } v;
  v.b = __float2bfloat16(x);
  return v.u;
}
DEV float fast_sig(float x) { return 1.0f / (1.0f + __expf(-x)); }
DEV float fast_tanh(float x) {
  float e = __expf(2.0f * x);
  return 1.0f - 2.0f / (e + 1.0f);
}

DEV void gload16(const void* g, void* l) {
  __builtin_amdgcn_global_load_lds(
      (const __attribute__((address_space(1))) void*)g,
      (__attribute__((address_space(3))) void*)l, 16, 0, 0);
}

// ---------------- custom device-scope grid barrier ----------------
// Monotonic arrival counter + epoch broadcast. Requires all blocks
// co-resident (guaranteed by hipLaunchCooperativeKernel) and state
// zeroed before launch (hipMemsetAsync in kernel_launch).
struct GBar {
  unsigned cnt;  unsigned pad0[31];
  unsigned epoch; unsigned pad1[31];
};

DEV void gbar(GBar* gb, unsigned e, int nblk) {
  __syncthreads();                 // compiler drains vmcnt before s_barrier
  if (threadIdx.x == 0) {
    __threadfence();               // release: L2 writeback, cross-XCD visible
    unsigned prev = __hip_atomic_fetch_add(&gb->cnt, 1u, __ATOMIC_RELAXED,
                                           __HIP_MEMORY_SCOPE_AGENT);
    if (prev == e * (unsigned)nblk - 1u) {
      __hip_atomic_store(&gb->epoch, e, __ATOMIC_RELAXED,
                         __HIP_MEMORY_SCOPE_AGENT);
    } else {
      while (__hip_atomic_load(&gb->epoch, __ATOMIC_RELAXED,
                               __HIP_MEMORY_SCOPE_AGENT) < e) {
        __builtin_amdgcn_s_sleep(2);
      }
    }
    __threadfence();               // acquire: invalidate stale L1/L2
  }
  __syncthreads();
}

// ---------------- LDS ----------------
struct GemmSm {
  unsigned short As[3][4096];
  unsigned short Bs[3][4096];
  float Pm[4][64];
  float Pl[4][64];
};
struct AttnSm { float qw[H]; float vw[H]; float sc[S]; float al[S]; };
struct LogZSm { float rm[256]; float rl[256]; };
union StepSm { GemmSm g; AttnSm a; LogZSm z; };

// ============ pipelined bf16 GEMM body (M=64, Ntile=64, BK=64) ============
template<bool PARTIALS>
DEV void gemm_body2(GemmSm& sm,
                    const unsigned short* __restrict__ A, int lda,
                    const unsigned short* __restrict__ W, int ldw,
                    int K, int n0,
                    float* __restrict__ C, size_t ldc,
                    const float* __restrict__ bias,
                    float* __restrict__ pm, float* __restrict__ pl, int pmb)
{
  const int tid = threadIdx.x;
  const int l   = tid & 63;
  const int w   = tid >> 6;

  f32x4 acc0 = {0,0,0,0}, acc1 = {0,0,0,0}, acc2 = {0,0,0,0}, acc3 = {0,0,0,0};

  const int rA = l & 15;
  const int kq = (l >> 4) << 3;

  auto stage = [&](int k0, int buf) {
    #pragma unroll
    for (int i = 0; i < 4; ++i) {
      const int c    = (w << 2) | i;
      const int side = c >> 3;
      const int ks   = (c >> 2) & 1;
      const int mb   = c & 3;
      const int kk   = k0 + ks * 32 + kq;
      const int row  = mb * 16 + rA;
      const unsigned short* src = side
        ? W + (size_t)(n0 + row) * ldw + kk
        : A + (size_t)row * lda + kk;
      unsigned short* dst = (side ? sm.Bs[buf] : sm.As[buf]) + ks * 2048 + mb * 512;
      gload16(src, dst);
    }
  };

  const int nk = K >> 6;
  stage(0, 0);
  if (nk > 1) stage(64, 1);
  for (int kt = 0; kt < nk; ++kt) {
    const int buf = kt % 3;
    if (kt + 2 < nk) {
      stage((kt + 2) << 6, (kt + 2) % 3);
      asm volatile("s_waitcnt vmcnt(8)" ::: "memory");
    } else if (kt + 1 < nk) {
      asm volatile("s_waitcnt vmcnt(4)" ::: "memory");
    } else {
      asm volatile("s_waitcnt vmcnt(0)" ::: "memory");
    }
    __builtin_amdgcn_s_barrier();
    asm volatile("" ::: "memory");
    const unsigned short* __restrict__ asb = sm.As[buf];
    const unsigned short* __restrict__ bsb = sm.Bs[buf];
    #pragma unroll
    for (int ks = 0; ks < 2; ++ks) {
      short8v bf = *(const short8v*)&bsb[ks * 2048 + (w << 9) + (l << 3)];
      acc0 = __builtin_amdgcn_mfma_f32_16x16x32_bf16(*(const short8v*)&asb[ks * 2048 + 0 * 512 + (l << 3)], bf, acc0, 0, 0, 0);
      acc1 = __builtin_amdgcn_mfma_f32_16x16x32_bf16(*(const short8v*)&asb[ks * 2048 + 1 * 512 + (l << 3)], bf, acc1, 0, 0, 0);
      acc2 = __builtin_amdgcn_mfma_f32_16x16x32_bf16(*(const short8v*)&asb[ks * 2048 + 2 * 512 + (l << 3)], bf, acc2, 0, 0, 0);
      acc3 = __builtin_amdgcn_mfma_f32_16x16x32_bf16(*(const short8v*)&asb[ks * 2048 + 3 * 512 + (l << 3)], bf, acc3, 0, 0, 0);
    }
    asm volatile("" ::: "memory");
    __builtin_amdgcn_s_barrier();
  }

  const int col = n0 + (w << 4) + (l & 15);
  const float bv = bias ? bias[col] : 0.0f;
  f32x4 accs[4] = {acc0, acc1, acc2, acc3};
  float vals[4][4];
  #pragma unroll
  for (int mb = 0; mb < 4; ++mb) {
    #pragma unroll
    for (int r = 0; r < 4; ++r) {
      int row = (mb << 4) + ((l >> 4) << 2) + r;
      float v = accs[mb][r] + bv;
      vals[mb][r] = v;
      C[(size_t)row * ldc + col] = v;
    }
  }

  if (PARTIALS) {
    #pragma unroll
    for (int mb = 0; mb < 4; ++mb) {
      #pragma unroll
      for (int r = 0; r < 4; ++r) {
        float v = vals[mb][r];
        float m = v;
        #pragma unroll
        for (int d = 1; d < 16; d <<= 1) m = fmaxf(m, __shfl_xor(m, d));
        float e = __expf(v - m);
        #pragma unroll
        for (int d = 1; d < 16; d <<= 1) e += __shfl_xor(e, d);
        if ((l & 15) == 0) {
          int row = (mb << 4) + ((l >> 4) << 2) + r;
          sm.Pm[w][row] = m;
          sm.Pl[w][row] = e;
        }
      }
    }
    __syncthreads();
    if (tid < 64) {
      float M = sm.Pm[0][tid];
      M = fmaxf(M, sm.Pm[1][tid]); M = fmaxf(M, sm.Pm[2][tid]); M = fmaxf(M, sm.Pm[3][tid]);
      float L = sm.Pl[0][tid] * __expf(sm.Pm[0][tid] - M)
              + sm.Pl[1][tid] * __expf(sm.Pm[1][tid] - M)
              + sm.Pl[2][tid] * __expf(sm.Pm[2][tid] - M)
              + sm.Pl[3][tid] * __expf(sm.Pm[3][tid] - M);
      pm[(size_t)pmb * 64 + tid] = M;
      pl[(size_t)pmb * 64 + tid] = L;
    }
    __syncthreads();
  }
}

// ---------------- persistent-kernel args ----------------
struct Args {
  const float *enc, *emb, *b1, *b2, *Vw, *Vb, *b_ih, *b_hh, *outb, *br1b, *br2b;
  const float *outW, *W_ih, *W_hh, *W1, *W2, *br1W, *br2W, *eh, *ec;
  const int* tok;
  unsigned short *outWb, *wihb, *whhb, *w1b, *W2b, *br1Wb, *br2Wb;
  unsigned short *enc0b, *ehb, *ecb, *hbf, *xbufb;
  float *keys, *cbuf0, *cbuf1, *qW1v, *gpart, *pmv, *plv, *logZ;
  float *out_lp, *out_h, *out_c, *out_at;
  GBar* bar;
};

DEV void cvt_range(const float* __restrict__ src, unsigned short* __restrict__ dst,
                   int n, int gtid, int gstride) {
  for (int i = gtid * 8; i < n; i += gstride * 8) {
    float4 a = *(const float4*)(src + i);
    float4 c = *(const float4*)(src + i + 4);
    ushort4 u1, u2;
    u1.x = f2bf(a.x); u1.y = f2bf(a.y); u1.z = f2bf(a.z); u1.w = f2bf(a.w);
    u2.x = f2bf(c.x); u2.y = f2bf(c.y); u2.z = f2bf(c.z); u2.w = f2bf(c.w);
    *(ushort4*)(dst + i)     = u1;
    *(ushort4*)(dst + i + 4) = u2;
  }
}

DEV void norm_apply(int j, float* __restrict__ lp_base, const float* __restrict__ logZ, int tid) {
  #pragma unroll
  for (int q = 0; q < 4; ++q) {
    size_t e = (size_t)j * 4096 + q * 1024 + tid * 4;
    int b = (int)(e / 32000);
    int r = (int)(e - (size_t)b * 32000);
    float4* p = (float4*)(lp_base + (size_t)b * T * V + r);
    float z = logZ[b];
    float4 v = *p;
    v.x -= z; v.y -= z; v.z -= z; v.w -= z;
    *p = v;
  }
}

DEV void logz_fn(LogZSm& z, const Args& a, int b, float* dst) {
  const int tid = threadIdx.x;
  float m1 = a.pmv[(size_t)tid * 64 + b];
  float l1 = a.plv[(size_t)tid * 64 + b];
  int j2 = tid + 256;
  if (j2 < NBL) {
    float m2 = a.pmv[(size_t)j2 * 64 + b], l2 = a.plv[(size_t)j2 * 64 + b];
    float M = fmaxf(m1, m2);
    l1 = l1 * __expf(m1 - M) + l2 * __expf(m2 - M);
    m1 = M;
  }
  z.rm[tid] = m1; z.rl[tid] = l1;
  __syncthreads();
  for (int off = 128; off > 0; off >>= 1) {
    if (tid < off) {
      float ma = z.rm[tid], mb2 = z.rm[tid + off];
      float M = fmaxf(ma, mb2);
      z.rl[tid] = z.rl[tid] * __expf(ma - M) + z.rl[tid + off] * __expf(mb2 - M);
      z.rm[tid] = M;
    }
    __syncthreads();
  }
  if (tid == 0) dst[b] = z.rm[0] + __logf(z.rl[0]);
  __syncthreads();
}

// fused scores+softmax+ctx+xbuf, one block per batch b
DEV void attn_fused(AttnSm& s, const Args& a, int b, int t) {
  const int tid = threadIdx.x;
  #pragma unroll
  for (int i = 0; i < 4; ++i) {
    int idx = tid + i * 256;
    s.qw[idx] = a.qW1v[b * H + idx];
    s.vw[idx] = a.Vw[idx];
  }
  __syncthreads();
  const int w = tid >> 6, lane = tid & 63;
  for (int si = 0; si < 32; ++si) {
    int sg = w * 32 + si;
    const float* kp = a.keys + (size_t)sg * H;
    float p = 0.0f;
    #pragma unroll
    for (int u = 0; u < 16; ++u) {
      int h = lane + (u << 6);
      p += s.vw[h] * fast_tanh(s.qw[h] + kp[h]);
    }
    #pragma unroll
    for (int d = 1; d < 64; d <<= 1) p += __shfl_xor(p, d);
    if (lane == 0) s.sc[sg] = p + a.Vb[0];
  }
  __syncthreads();
  if (tid < 64) {
    float a0 = s.sc[tid], a1 = s.sc[tid + 64];
    float m = fmaxf(a0, a1);
    #pragma unroll
    for (int d = 1; d < 64; d <<= 1) m = fmaxf(m, __shfl_xor(m, d));
    float e0 = __expf(a0 - m), e1 = __expf(a1 - m);
    float sum = e0 + e1;
    #pragma unroll
    for (int d = 1; d < 64; d <<= 1) sum += __shfl_xor(sum, d);
    float v0 = e0 / sum, v1 = e1 / sum;
    s.al[tid] = v0; s.al[tid + 64] = v1;
    a.out_at[((size_t)t * B + b) * S + tid]      = v0;
    a.out_at[((size_t)t * B + b) * S + tid + 64] = v1;
  }
  __syncthreads();
  float4 acc = {0, 0, 0, 0};
  const float* ep = a.enc + (size_t)b * S * H + tid * 4;
  for (int sx = 0; sx < S; ++sx) {
    float4 e4 = *(const float4*)(ep + (size_t)sx * H);
    float av = s.al[sx];
    acc.x += av * e4.x; acc.y += av * e4.y; acc.z += av * e4.z; acc.w += av * e4.w;
  }
  int token = a.tok[b * T + t];
  float4 em = *(const float4*)(a.emb + (size_t)token * H + tid * 4);
  ushort4 ue, uc;
  ue.x = f2bf(em.x);  ue.y = f2bf(em.y);  ue.z = f2bf(em.z);  ue.w = f2bf(em.w);
  uc.x = f2bf(acc.x); uc.y = f2bf(acc.y); uc.z = f2bf(acc.z); uc.w = f2bf(acc.w);
  unsigned short* xb = a.xbufb + (size_t)b * KX;
  *(ushort4*)(xb + tid * 4)         = ue;
  *(ushort4*)(xb + H + tid * 4)     = uc;
  *(ushort4*)(xb + 2 * H + tid * 4) = *(const ushort4*)(a.hbf + b * H + tid * 4);
}

DEV void cell_fn(const Args& a, int bx, int t) {
  const int tid = threadIdx.x;
  const int idx = bx * 256 + tid;
  const int b = idx >> 10, h = idx & 1023;
  const float* cp = (t & 1) ? a.cbuf1 : a.cbuf0;
  float* cn = (t & 1) ? a.cbuf0 : a.cbuf1;
  float gi = a.b_ih[h]         + a.b_hh[h];
  float gf = a.b_ih[H + h]     + a.b_hh[H + h];
  float gg = a.b_ih[2 * H + h] + a.b_hh[2 * H + h];
  float go = a.b_ih[3 * H + h] + a.b_hh[3 * H + h];
  #pragma unroll
  for (int p = 0; p < 6; ++p) {
    const float* g = a.gpart + (size_t)p * B * H4 + (size_t)b * H4;
    gi += g[h]; gf += g[H + h]; gg += g[2 * H + h]; go += g[3 * H + h];
  }
  float c = fast_sig(gf) * cp[idx] + fast_sig(gi) * fast_tanh(gg);
  float hv = fast_sig(go) * fast_tanh(c);
  cn[idx] = c;
  a.hbf[idx] = f2bf(hv);
  if (t == T - 1) { a.out_h[idx] = hv; a.out_c[idx] = c; }
}

// ============================ the persistent kernel ========================
__global__ __launch_bounds__(256, 2) void k_persist(Args a) {
  __shared__ StepSm sm;
  const int bx = blockIdx.x;
  const int tid = threadIdx.x;
  const int gtid = bx * 256 + tid;
  const int gstride = NBLK * 256;

  unsigned ep = 0;
  GBar* gb = a.bar;
  auto gsync = [&]() { gbar(gb, ++ep, NBLK); };

  // phase 0: all weight/activation conversions
  cvt_range(a.outW, a.outWb, V * H, gtid, gstride);
  cvt_range(a.W_ih, a.wihb, H4 * 2 * H, gtid, gstride);
  cvt_range(a.W_hh, a.whhb, H4 * H, gtid, gstride);
  cvt_range(a.W1,   a.w1b,   H * H, gtid, gstride);
  cvt_range(a.W2,   a.W2b,   H * H, gtid, gstride);
  cvt_range(a.br1W, a.br1Wb, H * H, gtid, gstride);
  cvt_range(a.br2W, a.br2Wb, H * H, gtid, gstride);
  cvt_range(a.enc,  a.enc0b, S * H, gtid, gstride);
  cvt_range(a.eh,   a.ehb,   B * H, gtid, gstride);
  cvt_range(a.ec,   a.ecb,   B * H, gtid, gstride);
  gsync();

  // phase 0.5: prep GEMMs
  if (bx < 16)
    gemm_body2<false>(sm.g, a.enc0b, H, a.W2b, H, H, bx * 64, a.keys, H, a.b2, nullptr, nullptr, 0);
  else if (bx < 32)
    gemm_body2<false>(sm.g, a.enc0b + 64 * H, H, a.W2b, H, H, (bx - 16) * 64, a.keys + 64 * H, H, a.b2, nullptr, nullptr, 0);
  else if (bx < 48)
    gemm_body2<false>(sm.g, a.ehb, H, a.br1Wb, H, H, (bx - 32) * 64, a.gpart, H, a.br1b, nullptr, nullptr, 0);
  else if (bx < 64)
    gemm_body2<false>(sm.g, a.ecb, H, a.br2Wb, H, H, (bx - 48) * 64, a.cbuf0, H, a.br2b, nullptr, nullptr, 0);
  gsync();

  // phase 0.75: hbf = bf16(h0)
  if (bx < 64) {
    int i4 = (bx * 256 + tid) * 4;
    float4 v = *(const float4*)(a.gpart + i4);
    ushort4 u;
    u.x = f2bf(v.x); u.y = f2bf(v.y); u.z = f2bf(v.z); u.w = f2bf(v.w);
    *(ushort4*)(a.hbf + i4) = u;
  }
  gsync();

  for (int t = 0; t < T; ++t) {
    // P1: qW1 (16) + logits(t-1) tiles 0..495
    if (bx < 16) {
      gemm_body2<false>(sm.g, a.hbf, H, a.w1b, H, H, bx * 64, a.qW1v, H, a.b1, nullptr, nullptr, 0);
    } else if (t > 0) {
      int tile = bx - 16;
      gemm_body2<true>(sm.g, a.hbf, H, a.outWb, H, H, tile * 64,
                       a.out_lp + (size_t)(t - 1) * V, (size_t)T * V, a.outb, a.pmv, a.plv, tile);
    }
    gsync();
    // P2: fused attn (64) + logits tiles 496..499 + norm(t-2)
    if (bx < 64) {
      attn_fused(sm.a, a, bx, t);
    } else if (bx < 68) {
      if (t > 0) {
        int tile = 496 + (bx - 64);
        gemm_body2<true>(sm.g, a.hbf, H, a.outWb, H, H, tile * 64,
                         a.out_lp + (size_t)(t - 1) * V, (size_t)T * V, a.outb, a.pmv, a.plv, tile);
      }
    } else if (t >= 2) {
      for (int j = bx - 68; j < 500; j += NBLK - 68)
        norm_apply(j, a.out_lp + (size_t)(t - 2) * V, a.logZ + ((t - 2) & 1) * B, tid);
    }
    gsync();
    // P3: gates split-K x6 (384) + logZ(t-1) (64)
    if (bx < 384) {
      const int kc = bx >> 6, nb = bx & 63;
      const unsigned short* A; const unsigned short* W; int ldw;
      if (kc < 4) { A = a.xbufb + kc * 512; W = a.wihb + kc * 512; ldw = 2 * H; }
      else        { A = a.xbufb + 2048 + (kc - 4) * 512; W = a.whhb + (kc - 4) * 512; ldw = H; }
      gemm_body2<false>(sm.g, A, KX, W, ldw, 512, nb * 64,
                        a.gpart + (size_t)kc * B * H4, (size_t)H4, nullptr, nullptr, nullptr, 0);
    } else if (bx < 448 && t > 0) {
      logz_fn(sm.z, a, bx - 384, a.logZ + ((t - 1) & 1) * B);
    }
    gsync();
    // P4: cell
    if (bx < 256) cell_fn(a, bx, t);
    gsync();
  }

  // finale: logits(T-1)
  if (bx < NBL)
    gemm_body2<true>(sm.g, a.hbf, H, a.outWb, H, H, bx * 64,
                     a.out_lp + (size_t)(T - 1) * V, (size_t)T * V, a.outb, a.pmv, a.plv, bx);
  gsync();
  if (bx < 64)
    logz_fn(sm.z, a, bx, a.logZ + ((T - 1) & 1) * B);
  else
    for (int j = bx - 64; j < 500; j += NBLK - 64)
      norm_apply(j, a.out_lp + (size_t)(T - 2) * V, a.logZ + ((T - 2) & 1) * B, tid);
  gsync();
  for (int j = bx; j < 500; j += NBLK)
    norm_apply(j, a.out_lp + (size_t)(T - 1) * V, a.logZ + ((T - 1) & 1) * B, tid);
}

// ================= legacy fallback kernels (R1-proven) =====================
__global__ __launch_bounds__(256) void k_f32_to_bf16(
    const float* __restrict__ src, unsigned short* __restrict__ dst, int n) {
  int i0 = (blockIdx.x * 256 + threadIdx.x) * 8;
  int stride = gridDim.x * 256 * 8;
  for (int i = i0; i < n; i += stride) {
    float4 a = *(const float4*)(src + i);
    float4 c = *(const float4*)(src + i + 4);
    ushort4 u1, u2;
    u1.x = f2bf(a.x); u1.y = f2bf(a.y); u1.z = f2bf(a.z); u1.w = f2bf(a.w);
    u2.x = f2bf(c.x); u2.y = f2bf(c.y); u2.z = f2bf(c.z); u2.w = f2bf(c.w);
    *(ushort4*)(dst + i)     = u1;
    *(ushort4*)(dst + i + 4) = u2;
  }
}

__global__ __launch_bounds__(256) void gemm64_mfma(
    const float* __restrict__ A, int lda,
    const void* __restrict__ Wa, int ldwa,
    const void* __restrict__ Wb, int ldwb, int ksplit,
    const float* __restrict__ bias1, const float* __restrict__ bias2,
    float* __restrict__ C, size_t ldc,
    int K, int wbf16,
    float* __restrict__ pm, float* __restrict__ pl)
{
  __shared__ unsigned short As[2048];
  __shared__ unsigned short Bs[2048];
  __shared__ float Pm[4][64];
  __shared__ float Pl[4][64];

  const int tid  = threadIdx.x;
  const int lane = tid & 63;
  const int w    = tid >> 6;
  const int n0   = blockIdx.x * 64;

  f32x4 acc0 = {0.f,0.f,0.f,0.f}, acc1 = {0.f,0.f,0.f,0.f};
  f32x4 acc2 = {0.f,0.f,0.f,0.f}, acc3 = {0.f,0.f,0.f,0.f};

  for (int k0 = 0; k0 < K; k0 += 32) {
    #pragma unroll
    for (int ss = 0; ss < 2; ++ss) {
      int s  = tid + ss * 256;
      int r  = s >> 3;
      int kq = s & 7;
      int kL = kq * 4;
      int kg = k0 + kL;
      const float* ap = A + (size_t)r * lda + kg;
      float4 av = *(const float4*)ap;
      ushort4 au;
      au.x = f2bf(av.x); au.y = f2bf(av.y); au.z = f2bf(av.z); au.w = f2bf(av.w);
      int dst = ((r >> 4) << 9) + ((kL >> 3) << 7) + ((r & 15) << 3) + (kL & 7);
      *(ushort4*)&As[dst] = au;
      int n = n0 + r;
      ushort4 bu;
      if (wbf16) {
        const unsigned short* wpp = (kg < ksplit)
          ? (const unsigned short*)Wa + (size_t)n * ldwa + kg
          : (const unsigned short*)Wb + (size_t)n * ldwb + (kg - ksplit);
        bu = *(const ushort4*)wpp;
      } else {
        const float* wpp = (kg < ksplit)
          ? (const float*)Wa + (size_t)n * ldwa + kg
          : (const float*)Wb + (size_t)n * ldwb + (kg - ksplit);
        float4 wv = *(const float4*)wpp;
        bu.x = f2bf(wv.x); bu.y = f2bf(wv.y); bu.z = f2bf(wv.z); bu.w = f2bf(wv.w);
      }
      *(ushort4*)&Bs[dst] = bu;
    }
    __syncthreads();
    short8v bf = *(const short8v*)&Bs[(w << 9) + (lane << 3)];
    short8v a0 = *(const short8v*)&As[(0 << 9) + (lane << 3)];
    short8v a1 = *(const short8v*)&As[(1 << 9) + (lane << 3)];
    short8v a2 = *(const short8v*)&As[(2 << 9) + (lane << 3)];
    short8v a3 = *(const short8v*)&As[(3 << 9) + (lane << 3)];
    acc0 = __builtin_amdgcn_mfma_f32_16x16x32_bf16(a0, bf, acc0, 0, 0, 0);
    acc1 = __builtin_amdgcn_mfma_f32_16x16x32_bf16(a1, bf, acc1, 0, 0, 0);
    acc2 = __builtin_amdgcn_mfma_f32_16x16x32_bf16(a2, bf, acc2, 0, 0, 0);
    acc3 = __builtin_amdgcn_mfma_f32_16x16x32_bf16(a3, bf, acc3, 0, 0, 0);
    __syncthreads();
  }

  const int col = n0 + (w << 4) + (lane & 15);
  const float bv = (bias1 ? bias1[col] : 0.0f) + (bias2 ? bias2[col] : 0.0f);
  f32x4 accs[4] = {acc0, acc1, acc2, acc3};
  float vals[4][4];
  #pragma unroll
  for (int mb = 0; mb < 4; ++mb) {
    #pragma unroll
    for (int r = 0; r < 4; ++r) {
      int row = (mb << 4) + ((lane >> 4) << 2) + r;
      float v = accs[mb][r] + bv;
      vals[mb][r] = v;
      C[(size_t)row * ldc + col] = v;
    }
  }

  if (pm) {
    #pragma unroll
    for (int mb = 0; mb < 4; ++mb) {
      #pragma unroll
      for (int r = 0; r < 4; ++r) {
        float v = vals[mb][r];
        float m = v;
        #pragma unroll
        for (int d = 1; d < 16; d <<= 1) m = fmaxf(m, __shfl_xor(m, d));
        float e = __expf(v - m);
        #pragma unroll
        for (int d = 1; d < 16; d <<= 1) e += __shfl_xor(e, d);
        if ((lane & 15) == 0) {
          int row = (mb << 4) + ((lane >> 4) << 2) + r;
          Pm[w][row] = m;
          Pl[w][row] = e;
        }
      }
    }
    __syncthreads();
    if (tid < 64) {
      float M = Pm[0][tid];
      M = fmaxf(M, Pm[1][tid]); M = fmaxf(M, Pm[2][tid]); M = fmaxf(M, Pm[3][tid]);
      float L = Pl[0][tid] * __expf(Pm[0][tid] - M)
              + Pl[1][tid] * __expf(Pm[1][tid] - M)
              + Pl[2][tid] * __expf(Pm[2][tid] - M)
              + Pl[3][tid] * __expf(Pm[3][tid] - M);
      pm[(size_t)blockIdx.x * 64 + tid] = M;
      pl[(size_t)blockIdx.x * 64 + tid] = L;
    }
  }
}

__global__ __launch_bounds__(256) void k_scores_leg(
    const float* __restrict__ qW1, const float* __restrict__ keys,
    const float* __restrict__ Vw, const float* __restrict__ Vb,
    float* __restrict__ scores)
{
  __shared__ float qw[H];
  __shared__ float vw[H];
  const int b  = blockIdx.x >> 2;
  const int sq = blockIdx.x & 3;
  const int tid = threadIdx.x;
  #pragma unroll
  for (int i = 0; i < 4; ++i) {
    qw[tid + i * 256] = qW1[b * H + tid + i * 256];
    vw[tid + i * 256] = Vw[tid + i * 256];
  }
  __syncthreads();
  const int w = tid >> 6, lane = tid & 63;
  #pragma unroll
  for (int si = 0; si < 8; ++si) {
    int sg = sq * 32 + w * 8 + si;
    const float* kp = keys + (size_t)sg * H;
    float p = 0.0f;
    #pragma unroll
    for (int u = 0; u < 16; ++u) {
      int h = lane + (u << 6);
      p += vw[h] * fast_tanh(qw[h] + kp[h]);
    }
    #pragma unroll
    for (int d = 1; d < 64; d <<= 1) p += __shfl_xor(p, d);
    if (lane == 0) scores[b * S + sg] = p + Vb[0];
  }
}

__global__ __launch_bounds__(256) void k_attn_ctx_leg(
    const float* __restrict__ scores, const float* __restrict__ enc,
    const float* __restrict__ emb, const int* __restrict__ tok,
    const float* __restrict__ hcur, float* __restrict__ xbuf,
    float* __restrict__ attn_out, int t)
{
  __shared__ float al[S];
  __shared__ float wred[4];
  const int b   = blockIdx.x >> 2;
  const int hq  = blockIdx.x & 3;
  const int tid = threadIdx.x;

  float sv = (tid < S) ? scores[b * S + tid] : -1e30f;
  float m = sv;
  #pragma unroll
  for (int d = 1; d < 64; d <<= 1) m = fmaxf(m, __shfl_xor(m, d));
  if ((tid & 63) == 0) wred[tid >> 6] = m;
  __syncthreads();
  m = fmaxf(fmaxf(wred[0], wred[1]), fmaxf(wred[2], wred[3]));
  float e = (tid < S) ? __expf(sv - m) : 0.0f;
  float ssum = e;
  #pragma unroll
  for (int d = 1; d < 64; d <<= 1) ssum += __shfl_xor(ssum, d);
  __syncthreads();
  if ((tid & 63) == 0) wred[tid >> 6] = ssum;
  __syncthreads();
  float tot = wred[0] + wred[1] + wred[2] + wred[3];
  float a = e / tot;
  if (tid < S) {
    al[tid] = a;
    if (hq == 0) attn_out[((size_t)t * B + b) * S + tid] = a;
  }
  __syncthreads();

  const int h = hq * 256 + tid;
  float acc = 0.0f;
  const float* ep = enc + (size_t)b * S * H + h;
  #pragma unroll 4
  for (int s = 0; s < S; ++s) acc += al[s] * ep[(size_t)s * H];

  int token = tok[b * T + t];
  xbuf[b * KX + h]         = emb[(size_t)token * H + h];
  xbuf[b * KX + H + h]     = acc;
  xbuf[b * KX + 2 * H + h] = hcur[b * H + h];
}

__global__ __launch_bounds__(256) void k_cell_leg(
    const float* __restrict__ gates, const float* __restrict__ cprev,
    float* __restrict__ hnew, float* __restrict__ cnew,
    float* __restrict__ hout, float* __restrict__ cout, int last)
{
  int idx = blockIdx.x * 256 + threadIdx.x;
  int b = idx >> 10, h = idx & 1023;
  const float* g = gates + (size_t)b * H4;
  float gi = g[h], gf = g[H + h], gg = g[2 * H + h], go = g[3 * H + h];
  float c = fast_sig(gf) * cprev[idx] + fast_sig(gi) * fast_tanh(gg);
  float hv = fast_sig(go) * fast_tanh(c);
  cnew[idx] = c;
  hnew[idx] = hv;
  if (last) { hout[idx] = hv; cout[idx] = c; }
}

__global__ __launch_bounds__(256) void k_norm_leg(
    const float* __restrict__ pm, const float* __restrict__ pl,
    float* __restrict__ lp, int t)
{
  __shared__ float rm[256], rl[256];
  const int bx = blockIdx.x;
  const int b  = bx / 125;
  const int ch = bx % 125;
  const int tid = threadIdx.x;

  float m1 = pm[(size_t)tid * 64 + b];
  float l1 = pl[(size_t)tid * 64 + b];
  int nb2 = tid + 256;
  if (nb2 < NBL) {
    float m2 = pm[(size_t)nb2 * 64 + b];
    float l2 = pl[(size_t)nb2 * 64 + b];
    float M = fmaxf(m1, m2);
    l1 = l1 * __expf(m1 - M) + l2 * __expf(m2 - M);
    m1 = M;
  }
  rm[tid] = m1; rl[tid] = l1;
  __syncthreads();
  for (int off = 128; off > 0; off >>= 1) {
    if (tid < off) {
      float ma = rm[tid], mb = rm[tid + off];
      float M = fmaxf(ma, mb);
      rl[tid] = rl[tid] * __expf(ma - M) + rl[tid + off] * __expf(mb - M);
      rm[tid] = M;
    }
    __syncthreads();
  }
  float logZ = rm[0] + __logf(rl[0]);
  size_t base = ((size_t)b * T + t) * V + (size_t)ch * 256;
  lp[base + tid] -= logZ;
}

// ============================ host launcher ================================
static void run_legacy(void* const* d_in, void* d_out, void* d_ws, size_t ws_size,
                       hipStream_t stream)
{
  const float* enc  = (const float*)d_in[0];
  const float* eh   = (const float*)d_in[1];
  const float* ec   = (const float*)d_in[2];
  const int*   tok  = (const int*)d_in[4];
  const float* emb  = (const float*)d_in[5];
  const float* W1   = (const float*)d_in[6];
  const float* b1   = (const float*)d_in[7];
  const float* W2   = (const float*)d_in[8];
  const float* b2   = (const float*)d_in[9];
  const float* Vw   = (const float*)d_in[10];
  const float* Vb   = (const float*)d_in[11];
  const float* W_ih = (const float*)d_in[12];
  const float* W_hh = (const float*)d_in[13];
  const float* b_ih = (const float*)d_in[14];
  const float* b_hh = (const float*)d_in[15];
  const float* outW = (const float*)d_in[16];
  const float* outb = (const float*)d_in[17];
  const float* br1W = (const float*)d_in[18];
  const float* br1b = (const float*)d_in[19];
  const float* br2W = (const float*)d_in[20];
  const float* br2b = (const float*)d_in[21];

  float* out    = (float*)d_out;
  float* out_h  = out + (size_t)B * T * V;
  float* out_c  = out_h + B * H;
  float* out_at = out_c + B * H;

  char* wp = (char*)d_ws;
  auto alloc = [&](size_t bytes) {
    char* p = wp; wp += (bytes + 255) & ~(size_t)255; return p;
  };
  float* keysL   = (float*)alloc((size_t)S * H * 4);
  float* hbuf0   = (float*)alloc((size_t)B * H * 4);
  float* hbuf1   = (float*)alloc((size_t)B * H * 4);
  float* cbuf0L  = (float*)alloc((size_t)B * H * 4);
  float* cbuf1L  = (float*)alloc((size_t)B * H * 4);
  float* qW1vL   = (float*)alloc((size_t)B * H * 4);
  float* scoresL = (float*)alloc((size_t)B * S * 4);
  float* xbuf    = (float*)alloc((size_t)B * KX * 4);
  float* gates   = (float*)alloc((size_t)B * H4 * 4);
  float* pmvL    = (float*)alloc((size_t)NBL * 64 * 4);
  float* plvL    = (float*)alloc((size_t)NBL * 64 * 4);
  unsigned short* outWbL = (unsigned short*)alloc((size_t)V * H * 2);
  size_t need_out = (size_t)(wp - (char*)d_ws);
  unsigned short* wihbL = (unsigned short*)alloc((size_t)H4 * 2 * H * 2);
  unsigned short* whhbL = (unsigned short*)alloc((size_t)H4 * H * 2);
  unsigned short* w1bL  = (unsigned short*)alloc((size_t)H * H * 2);
  size_t need_all = (size_t)(wp - (char*)d_ws);

  const bool cvtOut = ws_size >= need_out;
  const bool cvtAll = ws_size >= need_all;

  if (cvtOut) k_f32_to_bf16<<<4096, 256, 0, stream>>>(outW, outWbL, V * H);
  if (cvtAll) {
    k_f32_to_bf16<<<2048, 256, 0, stream>>>(W_ih, wihbL, H4 * 2 * H);
    k_f32_to_bf16<<<1024, 256, 0, stream>>>(W_hh, whhbL, H4 * H);
    k_f32_to_bf16<<<256, 256, 0, stream>>>(W1, w1bL, H * H);
  }

  gemm64_mfma<<<16, 256, 0, stream>>>(enc,          H, W2, H, W2, H, H, b2, nullptr, keysL,          H, H, 0, nullptr, nullptr);
  gemm64_mfma<<<16, 256, 0, stream>>>(enc + 64 * H, H, W2, H, W2, H, H, b2, nullptr, keysL + 64 * H, H, H, 0, nullptr, nullptr);
  gemm64_mfma<<<16, 256, 0, stream>>>(eh, H, br1W, H, br1W, H, H, br1b, nullptr, hbuf0, H, H, 0, nullptr, nullptr);
  gemm64_mfma<<<16, 256, 0, stream>>>(ec, H, br2W, H, br2W, H, H, br2b, nullptr, cbuf0L, H, H, 0, nullptr, nullptr);

  float* hb[2] = {hbuf0, hbuf1};
  float* cb[2] = {cbuf0L, cbuf1L};

  for (int t = 0; t < T; ++t) {
    const int cur = t & 1, nxt = cur ^ 1;
    if (cvtAll)
      gemm64_mfma<<<16, 256, 0, stream>>>(hb[cur], H, w1bL, H, w1bL, H, H, b1, nullptr, qW1vL, H, H, 1, nullptr, nullptr);
    else
      gemm64_mfma<<<16, 256, 0, stream>>>(hb[cur], H, W1, H, W1, H, H, b1, nullptr, qW1vL, H, H, 0, nullptr, nullptr);
    k_scores_leg<<<256, 256, 0, stream>>>(qW1vL, keysL, Vw, Vb, scoresL);
    k_attn_ctx_leg<<<256, 256, 0, stream>>>(scoresL, enc, emb, tok, hb[cur], xbuf, out_at, t);
    if (cvtAll)
      gemm64_mfma<<<64, 256, 0, stream>>>(xbuf, KX, wihbL, 2 * H, whhbL, H, 2 * H, b_ih, b_hh, gates, H4, KX, 1, nullptr, nullptr);
    else
      gemm64_mfma<<<64, 256, 0, stream>>>(xbuf, KX, W_ih, 2 * H, W_hh, H, 2 * H, b_ih, b_hh, gates, H4, KX, 0, nullptr, nullptr);
    k_cell_leg<<<256, 256, 0, stream>>>(gates, cb[cur], hb[nxt], cb[nxt], out_h, out_c, t == T - 1);
    if (cvtOut)
      gemm64_mfma<<<NBL, 256, 0, stream>>>(hb[nxt], H, outWbL, H, outWbL, H, H, outb, nullptr, out + (size_t)t * V, (size_t)T * V, H, 1, pmvL, plvL);
    else
      gemm64_mfma<<<NBL, 256, 0, stream>>>(hb[nxt], H, outW, H, outW, H, H, outb, nullptr, out + (size_t)t * V, (size_t)T * V, H, 0, pmvL, plvL);
    k_norm_leg<<<64 * 125, 256, 0, stream>>>(pmvL, plvL, out, t);
  }
}

extern "C" void kernel_launch(void* const* d_in, const int* in_sizes, int n_in,
                              void* d_out, int out_size, void* d_ws, size_t ws_size,
                              hipStream_t stream)
{
  (void)in_sizes; (void)n_in; (void)out_size;

  float* out = (float*)d_out;
  Args a;
  a.enc  = (const float*)d_in[0];
  a.eh   = (const float*)d_in[1];
  a.ec   = (const float*)d_in[2];
  a.tok  = (const int*)d_in[4];
  a.emb  = (const float*)d_in[5];
  a.W1   = (const float*)d_in[6];
  a.b1   = (const float*)d_in[7];
  a.W2   = (const float*)d_in[8];
  a.b2   = (const float*)d_in[9];
  a.Vw   = (const float*)d_in[10];
  a.Vb   = (const float*)d_in[11];
  a.W_ih = (const float*)d_in[12];
  a.W_hh = (const float*)d_in[13];
  a.b_ih = (const float*)d_in[14];
  a.b_hh = (const float*)d_in[15];
  a.outW = (const float*)d_in[16];
  a.outb = (const float*)d_in[17];
  a.br1W = (const float*)d_in[18];
  a.br1b = (const float*)d_in[19];
  a.br2W = (const float*)d_in[20];
  a.br2b = (const float*)d_in[21];

  a.out_lp = out;
  a.out_h  = out + (size_t)B * T * V;
  a.out_c  = a.out_h + B * H;
  a.out_at = a.out_c + B * H;

  char* wp = (char*)d_ws;
  auto alloc = [&](size_t bytes) {
    char* p = wp; wp += (bytes + 255) & ~(size_t)255; return p;
  };
  a.bar    = (GBar*)alloc(sizeof(GBar));
  a.keys   = (float*)alloc((size_t)S * H * 4);
  a.cbuf0  = (float*)alloc((size_t)B * H * 4);
  a.cbuf1  = (float*)alloc((size_t)B * H * 4);
  a.qW1v   = (float*)alloc((size_t)B * H * 4);
  a.xbufb  = (unsigned short*)alloc((size_t)B * KX * 2);
  a.gpart  = (float*)alloc((size_t)6 * B * H4 * 4);
  a.pmv    = (float*)alloc((size_t)NBL * 64 * 4);
  a.plv    = (float*)alloc((size_t)NBL * 64 * 4);
  a.logZ   = (float*)alloc((size_t)2 * B * 4);
  a.hbf    = (unsigned short*)alloc((size_t)B * H * 2);
  a.outWb  = (unsigned short*)alloc((size_t)V * H * 2);
  a.wihb   = (unsigned short*)alloc((size_t)H4 * 2 * H * 2);
  a.whhb   = (unsigned short*)alloc((size_t)H4 * H * 2);
  a.w1b    = (unsigned short*)alloc((size_t)H * H * 2);
  a.W2b    = (unsigned short*)alloc((size_t)H * H * 2);
  a.br1Wb  = (unsigned short*)alloc((size_t)H * H * 2);
  a.br2Wb  = (unsigned short*)alloc((size_t)H * H * 2);
  a.enc0b  = (unsigned short*)alloc((size_t)S * H * 2);
  a.ehb    = (unsigned short*)alloc((size_t)B * H * 2);
  a.ecb    = (unsigned short*)alloc((size_t)B * H * 2);
  size_t need_fast = (size_t)(wp - (char*)d_ws);

  if (ws_size >= need_fast) {
    hipError_t e0 = hipMemsetAsync(a.bar, 0, sizeof(GBar), stream);
    if (e0 == hipSuccess) {
      void* kargs[] = { (void*)&a };
      hipError_t err = hipLaunchCooperativeKernel(
          (const void*)k_persist, dim3(NBLK), dim3(256), kargs, 0, stream);
      if (err == hipSuccess) return;
    }
  }
  run_legacy(d_in, d_out, d_ws, ws_size, stream);
}

// Round 6
// 3232.964 us; speedup vs baseline: 6.6741x; 3.3573x over previous
//
#include <hip/hip_runtime.h>
#include <hip/hip_bf16.h>

#define DEV __device__ __forceinline__

constexpr int B = 64, S = 128, T = 32, H = 1024, V = 32000;
constexpr int H4 = 4096;          // 4*H
constexpr int KX = 3072;          // [emb | ctx | h]
constexpr int NBL = V / 64;       // 500 logits N-tiles
constexpr int BH = B * H;

using f32x4   = __attribute__((ext_vector_type(4))) float;
using short8v = __attribute__((ext_vector_type(8))) short;

DEV unsigned short f2bf(float x) {
  union { __hip_bfloat16 b; unsigned short u; } v;
  v.b = __float2bfloat16(x);
  return v.u;
}
DEV float fast_sig(float x) { return 1.0f / (1.0f + __expf(-x)); }
DEV float fast_tanh(float x) {
  float e = __expf(2.0f * x);
  return 1.0f - 2.0f / (e + 1.0f);
}

DEV void gload16(const void* g, void* l) {
  __builtin_amdgcn_global_load_lds(
      (const __attribute__((address_space(1))) void*)g,
      (__attribute__((address_space(3))) void*)l, 16, 0, 0);
}

// ---------------- LDS ----------------
struct GemmSm {
  unsigned short As[3][4096];
  unsigned short Bs[3][4096];
  float Pm[4][64];
  float Pl[4][64];
};
struct AttnSm { float qw[H]; float vw[H]; float sc[S]; float al[S]; };

// ============ pipelined bf16 GEMM body (M=64, Ntile=64, BK=64) ============
// verified fragment layout: lane l's 16B at l*16 -> row=mb*16+(l&15),
// k=ks*32+(l>>4)*8..+7 ; 3 LDS buffers, 2-deep prefetch, counted vmcnt.
template<bool PARTIALS>
DEV void gemm_body2(GemmSm& sm,
                    const unsigned short* __restrict__ A, int lda,
                    const unsigned short* __restrict__ W, int ldw,
                    int K, int n0,
                    float* __restrict__ C, size_t ldc,
                    const float* __restrict__ bias,
                    float* __restrict__ pm, float* __restrict__ pl, int pmb)
{
  const int tid = threadIdx.x;
  const int l   = tid & 63;
  const int w   = tid >> 6;

  f32x4 acc0 = {0,0,0,0}, acc1 = {0,0,0,0}, acc2 = {0,0,0,0}, acc3 = {0,0,0,0};

  const int rA = l & 15;
  const int kq = (l >> 4) << 3;

  auto stage = [&](int k0, int buf) {
    #pragma unroll
    for (int i = 0; i < 4; ++i) {
      const int c    = (w << 2) | i;
      const int side = c >> 3;
      const int ks   = (c >> 2) & 1;
      const int mb   = c & 3;
      const int kk   = k0 + ks * 32 + kq;
      const int row  = mb * 16 + rA;
      const unsigned short* src = side
        ? W + (size_t)(n0 + row) * ldw + kk
        : A + (size_t)row * lda + kk;
      unsigned short* dst = (side ? sm.Bs[buf] : sm.As[buf]) + ks * 2048 + mb * 512;
      gload16(src, dst);
    }
  };

  const int nk = K >> 6;
  stage(0, 0);
  if (nk > 1) stage(64, 1);
  for (int kt = 0; kt < nk; ++kt) {
    const int buf = kt % 3;
    if (kt + 2 < nk) {
      stage((kt + 2) << 6, (kt + 2) % 3);
      asm volatile("s_waitcnt vmcnt(8)" ::: "memory");
    } else if (kt + 1 < nk) {
      asm volatile("s_waitcnt vmcnt(4)" ::: "memory");
    } else {
      asm volatile("s_waitcnt vmcnt(0)" ::: "memory");
    }
    __builtin_amdgcn_s_barrier();
    asm volatile("" ::: "memory");
    const unsigned short* __restrict__ asb = sm.As[buf];
    const unsigned short* __restrict__ bsb = sm.Bs[buf];
    #pragma unroll
    for (int ks = 0; ks < 2; ++ks) {
      short8v bf = *(const short8v*)&bsb[ks * 2048 + (w << 9) + (l << 3)];
      acc0 = __builtin_amdgcn_mfma_f32_16x16x32_bf16(*(const short8v*)&asb[ks * 2048 + 0 * 512 + (l << 3)], bf, acc0, 0, 0, 0);
      acc1 = __builtin_amdgcn_mfma_f32_16x16x32_bf16(*(const short8v*)&asb[ks * 2048 + 1 * 512 + (l << 3)], bf, acc1, 0, 0, 0);
      acc2 = __builtin_amdgcn_mfma_f32_16x16x32_bf16(*(const short8v*)&asb[ks * 2048 + 2 * 512 + (l << 3)], bf, acc2, 0, 0, 0);
      acc3 = __builtin_amdgcn_mfma_f32_16x16x32_bf16(*(const short8v*)&asb[ks * 2048 + 3 * 512 + (l << 3)], bf, acc3, 0, 0, 0);
    }
    asm volatile("" ::: "memory");
    __builtin_amdgcn_s_barrier();
  }

  const int col = n0 + (w << 4) + (l & 15);
  const float bv = bias ? bias[col] : 0.0f;
  f32x4 accs[4] = {acc0, acc1, acc2, acc3};
  float vals[4][4];
  #pragma unroll
  for (int mb = 0; mb < 4; ++mb) {
    #pragma unroll
    for (int r = 0; r < 4; ++r) {
      int row = (mb << 4) + ((l >> 4) << 2) + r;
      float v = accs[mb][r] + bv;
      vals[mb][r] = v;
      C[(size_t)row * ldc + col] = v;
    }
  }

  if (PARTIALS) {
    #pragma unroll
    for (int mb = 0; mb < 4; ++mb) {
      #pragma unroll
      for (int r = 0; r < 4; ++r) {
        float v = vals[mb][r];
        float m = v;
        #pragma unroll
        for (int d = 1; d < 16; d <<= 1) m = fmaxf(m, __shfl_xor(m, d));
        float e = __expf(v - m);
        #pragma unroll
        for (int d = 1; d < 16; d <<= 1) e += __shfl_xor(e, d);
        if ((l & 15) == 0) {
          int row = (mb << 4) + ((l >> 4) << 2) + r;
          sm.Pm[w][row] = m;
          sm.Pl[w][row] = e;
        }
      }
    }
    __syncthreads();
    if (tid < 64) {
      float M = sm.Pm[0][tid];
      M = fmaxf(M, sm.Pm[1][tid]); M = fmaxf(M, sm.Pm[2][tid]); M = fmaxf(M, sm.Pm[3][tid]);
      float L = sm.Pl[0][tid] * __expf(sm.Pm[0][tid] - M)
              + sm.Pl[1][tid] * __expf(sm.Pm[1][tid] - M)
              + sm.Pl[2][tid] * __expf(sm.Pm[2][tid] - M)
              + sm.Pl[3][tid] * __expf(sm.Pm[3][tid] - M);
      pm[(size_t)pmb * 64 + tid] = M;
      pl[(size_t)pmb * 64 + tid] = L;
    }
    __syncthreads();
  }
}

// ============ legacy (R1-verified) f32-staging GEMM body, parameterized ====
DEV void legacy_body(unsigned short* As, unsigned short* Bs,
                     float (*Pm)[64], float (*Pl)[64],
                     const float* __restrict__ A, int lda,
                     const void* __restrict__ Wa, int ldwa,
                     const void* __restrict__ Wb, int ldwb, int ksplit,
                     const float* __restrict__ bias1, const float* __restrict__ bias2,
                     float* __restrict__ C, size_t ldc,
                     int K, int wbf16,
                     float* __restrict__ pm, float* __restrict__ pl,
                     int n0, int pmb)
{
  const int tid  = threadIdx.x;
  const int lane = tid & 63;
  const int w    = tid >> 6;

  f32x4 acc0 = {0.f,0.f,0.f,0.f}, acc1 = {0.f,0.f,0.f,0.f};
  f32x4 acc2 = {0.f,0.f,0.f,0.f}, acc3 = {0.f,0.f,0.f,0.f};

  for (int k0 = 0; k0 < K; k0 += 32) {
    #pragma unroll
    for (int ss = 0; ss < 2; ++ss) {
      int s  = tid + ss * 256;
      int r  = s >> 3;
      int kq = s & 7;
      int kL = kq * 4;
      int kg = k0 + kL;
      const float* ap = A + (size_t)r * lda + kg;
      float4 av = *(const float4*)ap;
      ushort4 au;
      au.x = f2bf(av.x); au.y = f2bf(av.y); au.z = f2bf(av.z); au.w = f2bf(av.w);
      int dst = ((r >> 4) << 9) + ((kL >> 3) << 7) + ((r & 15) << 3) + (kL & 7);
      *(ushort4*)&As[dst] = au;
      int n = n0 + r;
      ushort4 bu;
      if (wbf16) {
        const unsigned short* wpp = (kg < ksplit)
          ? (const unsigned short*)Wa + (size_t)n * ldwa + kg
          : (const unsigned short*)Wb + (size_t)n * ldwb + (kg - ksplit);
        bu = *(const ushort4*)wpp;
      } else {
        const float* wpp = (kg < ksplit)
          ? (const float*)Wa + (size_t)n * ldwa + kg
          : (const float*)Wb + (size_t)n * ldwb + (kg - ksplit);
        float4 wv = *(const float4*)wpp;
        bu.x = f2bf(wv.x); bu.y = f2bf(wv.y); bu.z = f2bf(wv.z); bu.w = f2bf(wv.w);
      }
      *(ushort4*)&Bs[dst] = bu;
    }
    __syncthreads();
    short8v bf = *(const short8v*)&Bs[(w << 9) + (lane << 3)];
    short8v a0 = *(const short8v*)&As[(0 << 9) + (lane << 3)];
    short8v a1 = *(const short8v*)&As[(1 << 9) + (lane << 3)];
    short8v a2 = *(const short8v*)&As[(2 << 9) + (lane << 3)];
    short8v a3 = *(const short8v*)&As[(3 << 9) + (lane << 3)];
    acc0 = __builtin_amdgcn_mfma_f32_16x16x32_bf16(a0, bf, acc0, 0, 0, 0);
    acc1 = __builtin_amdgcn_mfma_f32_16x16x32_bf16(a1, bf, acc1, 0, 0, 0);
    acc2 = __builtin_amdgcn_mfma_f32_16x16x32_bf16(a2, bf, acc2, 0, 0, 0);
    acc3 = __builtin_amdgcn_mfma_f32_16x16x32_bf16(a3, bf, acc3, 0, 0, 0);
    __syncthreads();
  }

  const int col = n0 + (w << 4) + (lane & 15);
  const float bv = (bias1 ? bias1[col] : 0.0f) + (bias2 ? bias2[col] : 0.0f);
  f32x4 accs[4] = {acc0, acc1, acc2, acc3};
  float vals[4][4];
  #pragma unroll
  for (int mb = 0; mb < 4; ++mb) {
    #pragma unroll
    for (int r = 0; r < 4; ++r) {
      int row = (mb << 4) + ((lane >> 4) << 2) + r;
      float v = accs[mb][r] + bv;
      vals[mb][r] = v;
      C[(size_t)row * ldc + col] = v;
    }
  }

  if (pm) {
    #pragma unroll
    for (int mb = 0; mb < 4; ++mb) {
      #pragma unroll
      for (int r = 0; r < 4; ++r) {
        float v = vals[mb][r];
        float m = v;
        #pragma unroll
        for (int d = 1; d < 16; d <<= 1) m = fmaxf(m, __shfl_xor(m, d));
        float e = __expf(v - m);
        #pragma unroll
        for (int d = 1; d < 16; d <<= 1) e += __shfl_xor(e, d);
        if ((lane & 15) == 0) {
          int row = (mb << 4) + ((lane >> 4) << 2) + r;
          Pm[w][row] = m;
          Pl[w][row] = e;
        }
      }
    }
    __syncthreads();
    if (tid < 64) {
      float M = Pm[0][tid];
      M = fmaxf(M, Pm[1][tid]); M = fmaxf(M, Pm[2][tid]); M = fmaxf(M, Pm[3][tid]);
      float L = Pl[0][tid] * __expf(Pm[0][tid] - M)
              + Pl[1][tid] * __expf(Pm[1][tid] - M)
              + Pl[2][tid] * __expf(Pm[2][tid] - M)
              + Pl[3][tid] * __expf(Pm[3][tid] - M);
      pm[(size_t)pmb * 64 + tid] = M;
      pl[(size_t)pmb * 64 + tid] = L;
    }
  }
}

__global__ __launch_bounds__(256) void gemm64_mfma(
    const float* __restrict__ A, int lda,
    const void* __restrict__ Wa, int ldwa,
    const void* __restrict__ Wb, int ldwb, int ksplit,
    const float* __restrict__ bias1, const float* __restrict__ bias2,
    float* __restrict__ C, size_t ldc,
    int K, int wbf16,
    float* __restrict__ pm, float* __restrict__ pl)
{
  __shared__ unsigned short As[2048];
  __shared__ unsigned short Bs[2048];
  __shared__ float Pm[4][64];
  __shared__ float Pl[4][64];
  legacy_body(As, Bs, Pm, Pl, A, lda, Wa, ldwa, Wb, ldwb, ksplit,
              bias1, bias2, C, ldc, K, wbf16, pm, pl,
              blockIdx.x * 64, blockIdx.x);
}

// f32 -> bf16 bulk convert
__global__ __launch_bounds__(256) void k_f32_to_bf16(
    const float* __restrict__ src, unsigned short* __restrict__ dst, int n) {
  int i0 = (blockIdx.x * 256 + threadIdx.x) * 8;
  int stride = gridDim.x * 256 * 8;
  for (int i = i0; i < n; i += stride) {
    float4 a = *(const float4*)(src + i);
    float4 c = *(const float4*)(src + i + 4);
    ushort4 u1, u2;
    u1.x = f2bf(a.x); u1.y = f2bf(a.y); u1.z = f2bf(a.z); u1.w = f2bf(a.w);
    u2.x = f2bf(c.x); u2.y = f2bf(c.y); u2.z = f2bf(c.z); u2.w = f2bf(c.w);
    *(ushort4*)(dst + i)     = u1;
    *(ushort4*)(dst + i + 4) = u2;
  }
}

// ---------------- per-step kernels (fast path) ----------------
// qW1 split-K x4: grid 64, kc=bx>>4, partials into qW1p[kc][B][H]
__global__ __launch_bounds__(256) void k_qw1x(
    const unsigned short* __restrict__ hbt, const unsigned short* __restrict__ w1b,
    float* __restrict__ qW1p)
{
  __shared__ GemmSm sm;
  const int kc = blockIdx.x >> 4, nb = blockIdx.x & 15;
  gemm_body2<false>(sm, hbt + kc * 256, H, w1b + kc * 256, H, 256, nb * 64,
                    qW1p + (size_t)kc * BH, H, nullptr, nullptr, nullptr, 0);
}

// fused scores+softmax+ctx+xbuf: grid 256 (b x h-quarter)
__global__ __launch_bounds__(256) void k_attn2(
    const float* __restrict__ qW1p, const float* __restrict__ b1,
    const float* __restrict__ keys, const float* __restrict__ Vw,
    const float* __restrict__ Vb,
    const float* __restrict__ enc, const float* __restrict__ emb,
    const int* __restrict__ tok,
    const unsigned short* __restrict__ hbt, unsigned short* __restrict__ xbufb,
    float* __restrict__ attn_out, int t)
{
  __shared__ AttnSm s;
  const int tid = threadIdx.x;
  const int b = blockIdx.x >> 2, hq = blockIdx.x & 3;

  #pragma unroll
  for (int i = 0; i < 4; ++i) {
    int idx = tid + i * 256;
    float q = b1[idx];
    q += qW1p[(size_t)0 * BH + b * H + idx];
    q += qW1p[(size_t)1 * BH + b * H + idx];
    q += qW1p[(size_t)2 * BH + b * H + idx];
    q += qW1p[(size_t)3 * BH + b * H + idx];
    s.qw[idx] = q;
    s.vw[idx] = Vw[idx];
  }
  __syncthreads();

  const int w = tid >> 6, lane = tid & 63;
  #pragma unroll
  for (int si = 0; si < 32; ++si) {
    int sg = w * 32 + si;
    const float* kp = keys + (size_t)sg * H;
    float p = 0.0f;
    #pragma unroll
    for (int u = 0; u < 16; ++u) {
      int h = lane + (u << 6);
      p += s.vw[h] * fast_tanh(s.qw[h] + kp[h]);
    }
    #pragma unroll
    for (int d = 1; d < 64; d <<= 1) p += __shfl_xor(p, d);
    if (lane == 0) s.sc[sg] = p + Vb[0];
  }
  __syncthreads();
  if (tid < 64) {
    float a0 = s.sc[tid], a1 = s.sc[tid + 64];
    float m = fmaxf(a0, a1);
    #pragma unroll
    for (int d = 1; d < 64; d <<= 1) m = fmaxf(m, __shfl_xor(m, d));
    float e0 = __expf(a0 - m), e1 = __expf(a1 - m);
    float sum = e0 + e1;
    #pragma unroll
    for (int d = 1; d < 64; d <<= 1) sum += __shfl_xor(sum, d);
    float v0 = e0 / sum, v1 = e1 / sum;
    s.al[tid] = v0; s.al[tid + 64] = v1;
    if (hq == 0) {
      attn_out[((size_t)t * B + b) * S + tid]      = v0;
      attn_out[((size_t)t * B + b) * S + tid + 64] = v1;
    }
  }
  __syncthreads();

  const int h = hq * 256 + tid;
  float acc = 0.0f;
  const float* ep = enc + (size_t)b * S * H + h;
  #pragma unroll 4
  for (int sx = 0; sx < S; ++sx) acc += s.al[sx] * ep[(size_t)sx * H];

  int token = tok[b * T + t];
  xbufb[(size_t)b * KX + h]         = f2bf(emb[(size_t)token * H + h]);
  xbufb[(size_t)b * KX + H + h]     = f2bf(acc);
  xbufb[(size_t)b * KX + 2 * H + h] = hbt[b * H + h];
}

// gates split-K x6: grid 384
__global__ __launch_bounds__(256) void k_gates2(
    const unsigned short* __restrict__ xbufb,
    const unsigned short* __restrict__ wihb,
    const unsigned short* __restrict__ whhb,
    float* __restrict__ gpart)
{
  __shared__ GemmSm sm;
  const int kc = blockIdx.x >> 6, nb = blockIdx.x & 63;
  const unsigned short* A;
  const unsigned short* W;
  int ldw;
  if (kc < 4) { A = xbufb + kc * 512; W = wihb + kc * 512; ldw = 2 * H; }
  else        { A = xbufb + 2048 + (kc - 4) * 512; W = whhb + (kc - 4) * 512; ldw = H; }
  gemm_body2<false>(sm, A, KX, W, ldw, 512, nb * 64,
                    gpart + (size_t)kc * B * H4, (size_t)H4, nullptr, nullptr, nullptr, 0);
}

// cell: sum 6 partials + biases; write c, h history (bf16 + f32)
__global__ __launch_bounds__(256) void k_cell2(
    const float* __restrict__ gpart, const float* __restrict__ b_ih,
    const float* __restrict__ b_hh, const float* __restrict__ cprev,
    float* __restrict__ cnew, unsigned short* __restrict__ hb_next,
    float* __restrict__ hf_next,
    float* __restrict__ out_h, float* __restrict__ out_c, int last)
{
  const int idx = blockIdx.x * 256 + threadIdx.x;
  const int b = idx >> 10, h = idx & 1023;
  float gi = b_ih[h]         + b_hh[h];
  float gf = b_ih[H + h]     + b_hh[H + h];
  float gg = b_ih[2 * H + h] + b_hh[2 * H + h];
  float go = b_ih[3 * H + h] + b_hh[3 * H + h];
  #pragma unroll
  for (int p = 0; p < 6; ++p) {
    const float* g = gpart + (size_t)p * B * H4 + (size_t)b * H4;
    gi += g[h]; gf += g[H + h]; gg += g[2 * H + h]; go += g[3 * H + h];
  }
  float c = fast_sig(gf) * cprev[idx] + fast_sig(gi) * fast_tanh(gg);
  float hv = fast_sig(go) * fast_tanh(c);
  cnew[idx] = c;
  hb_next[idx] = f2bf(hv);
  hf_next[idx] = hv;
  if (last) { out_h[idx] = hv; out_c[idx] = c; }
}

// ---------------- batched logits finale ----------------
// fast: bf16 weights + bf16 h-history; grid 16000 (nt = bx>>5, mt = bx&31)
__global__ __launch_bounds__(256) void k_biglogits_fast(
    const unsigned short* __restrict__ hhb,   // hhist slots 1..32 (2048 x H)
    const unsigned short* __restrict__ outWb,
    const float* __restrict__ outb, float* __restrict__ lp,
    float* __restrict__ pm, float* __restrict__ pl)
{
  __shared__ GemmSm sm;
  const int mt = blockIdx.x & 31, nt = blockIdx.x >> 5;
  gemm_body2<true>(sm, hhb + (size_t)mt * 64 * H, H, outWb, H, H, nt * 64,
                   lp + (size_t)mt * V, (size_t)T * V, outb, pm, pl, nt * 32 + mt);
}

// mid: f32 weights + f32 h-history via legacy body
__global__ __launch_bounds__(256) void k_biglogits_leg(
    const float* __restrict__ hhf, const float* __restrict__ outW,
    const float* __restrict__ outb, float* __restrict__ lp,
    float* __restrict__ pm, float* __restrict__ pl)
{
  __shared__ unsigned short As[2048];
  __shared__ unsigned short Bs[2048];
  __shared__ float Pm[4][64];
  __shared__ float Pl[4][64];
  const int mt = blockIdx.x & 31, nt = blockIdx.x >> 5;
  legacy_body(As, Bs, Pm, Pl, hhf + (size_t)mt * 64 * H, H,
              outW, H, outW, H, H, outb, nullptr,
              lp + (size_t)mt * V, (size_t)T * V, H, 0, pm, pl,
              nt * 64, nt * 32 + mt);
}

// logZ over 500 N-tiles: grid 2048 (r = m*64+b)
__global__ __launch_bounds__(256) void k_logz2(
    const float* __restrict__ pm, const float* __restrict__ pl,
    float* __restrict__ logZ2)
{
  __shared__ float rm[256], rl[256];
  const int r = blockIdx.x;
  const int tid = threadIdx.x;
  float m1 = pm[(size_t)tid * 2048 + r];
  float l1 = pl[(size_t)tid * 2048 + r];
  int j2 = tid + 256;
  if (j2 < NBL) {
    float m2 = pm[(size_t)j2 * 2048 + r], l2 = pl[(size_t)j2 * 2048 + r];
    float M = fmaxf(m1, m2);
    l1 = l1 * __expf(m1 - M) + l2 * __expf(m2 - M);
    m1 = M;
  }
  rm[tid] = m1; rl[tid] = l1;
  __syncthreads();
  for (int off = 128; off > 0; off >>= 1) {
    if (tid < off) {
      float ma = rm[tid], mb2 = rm[tid + off];
      float M = fmaxf(ma, mb2);
      rl[tid] = rl[tid] * __expf(ma - M) + rl[tid + off] * __expf(mb2 - M);
      rm[tid] = M;
    }
    __syncthreads();
  }
  if (tid == 0) logZ2[r] = rm[0] + __logf(rl[0]);
}

// normalize: grid 16000, 4096 floats/block over flat [b][t][v]
__global__ __launch_bounds__(256) void k_norm2(
    float* __restrict__ lp, const float* __restrict__ logZ2)
{
  const int tid = threadIdx.x;
  #pragma unroll
  for (int q = 0; q < 4; ++q) {
    size_t e = (size_t)blockIdx.x * 4096 + q * 1024 + tid * 4;
    int b  = (int)(e / ((size_t)T * V));
    int rem = (int)(e - (size_t)b * T * V);
    int t  = rem / V;
    float z = logZ2[t * 64 + b];
    float4* p = (float4*)(lp + e);
    float4 v = *p;
    v.x -= z; v.y -= z; v.z -= z; v.w -= z;
    *p = v;
  }
}

// ================= legacy fallback kernels (R1-proven) =====================
__global__ __launch_bounds__(256) void k_scores_leg(
    const float* __restrict__ qW1, const float* __restrict__ keys,
    const float* __restrict__ Vw, const float* __restrict__ Vb,
    float* __restrict__ scores)
{
  __shared__ float qw[H];
  __shared__ float vw[H];
  const int b  = blockIdx.x >> 2;
  const int sq = blockIdx.x & 3;
  const int tid = threadIdx.x;
  #pragma unroll
  for (int i = 0; i < 4; ++i) {
    qw[tid + i * 256] = qW1[b * H + tid + i * 256];
    vw[tid + i * 256] = Vw[tid + i * 256];
  }
  __syncthreads();
  const int w = tid >> 6, lane = tid & 63;
  #pragma unroll
  for (int si = 0; si < 8; ++si) {
    int sg = sq * 32 + w * 8 + si;
    const float* kp = keys + (size_t)sg * H;
    float p = 0.0f;
    #pragma unroll
    for (int u = 0; u < 16; ++u) {
      int h = lane + (u << 6);
      p += vw[h] * fast_tanh(qw[h] + kp[h]);
    }
    #pragma unroll
    for (int d = 1; d < 64; d <<= 1) p += __shfl_xor(p, d);
    if (lane == 0) scores[b * S + sg] = p + Vb[0];
  }
}

__global__ __launch_bounds__(256) void k_attn_ctx_leg(
    const float* __restrict__ scores, const float* __restrict__ enc,
    const float* __restrict__ emb, const int* __restrict__ tok,
    const float* __restrict__ hcur, float* __restrict__ xbuf,
    float* __restrict__ attn_out, int t)
{
  __shared__ float al[S];
  __shared__ float wred[4];
  const int b   = blockIdx.x >> 2;
  const int hq  = blockIdx.x & 3;
  const int tid = threadIdx.x;

  float sv = (tid < S) ? scores[b * S + tid] : -1e30f;
  float m = sv;
  #pragma unroll
  for (int d = 1; d < 64; d <<= 1) m = fmaxf(m, __shfl_xor(m, d));
  if ((tid & 63) == 0) wred[tid >> 6] = m;
  __syncthreads();
  m = fmaxf(fmaxf(wred[0], wred[1]), fmaxf(wred[2], wred[3]));
  float e = (tid < S) ? __expf(sv - m) : 0.0f;
  float ssum = e;
  #pragma unroll
  for (int d = 1; d < 64; d <<= 1) ssum += __shfl_xor(ssum, d);
  __syncthreads();
  if ((tid & 63) == 0) wred[tid >> 6] = ssum;
  __syncthreads();
  float tot = wred[0] + wred[1] + wred[2] + wred[3];
  float a = e / tot;
  if (tid < S) {
    al[tid] = a;
    if (hq == 0) attn_out[((size_t)t * B + b) * S + tid] = a;
  }
  __syncthreads();

  const int h = hq * 256 + tid;
  float acc = 0.0f;
  const float* ep = enc + (size_t)b * S * H + h;
  #pragma unroll 4
  for (int s = 0; s < S; ++s) acc += al[s] * ep[(size_t)s * H];

  int token = tok[b * T + t];
  xbuf[b * KX + h]         = emb[(size_t)token * H + h];
  xbuf[b * KX + H + h]     = acc;
  xbuf[b * KX + 2 * H + h] = hcur[b * H + h];
}

__global__ __launch_bounds__(256) void k_cell_leg(
    const float* __restrict__ gates, const float* __restrict__ cprev,
    float* __restrict__ hnew, float* __restrict__ cnew,
    float* __restrict__ hout, float* __restrict__ cout, int last)
{
  int idx = blockIdx.x * 256 + threadIdx.x;
  int b = idx >> 10, h = idx & 1023;
  const float* g = gates + (size_t)b * H4;
  float gi = g[h], gf = g[H + h], gg = g[2 * H + h], go = g[3 * H + h];
  float c = fast_sig(gf) * cprev[idx] + fast_sig(gi) * fast_tanh(gg);
  float hv = fast_sig(go) * fast_tanh(c);
  cnew[idx] = c;
  hnew[idx] = hv;
  if (last) { hout[idx] = hv; cout[idx] = c; }
}

__global__ __launch_bounds__(256) void k_norm_leg(
    const float* __restrict__ pm, const float* __restrict__ pl,
    float* __restrict__ lp, int t)
{
  __shared__ float rm[256], rl[256];
  const int bx = blockIdx.x;
  const int b  = bx / 125;
  const int ch = bx % 125;
  const int tid = threadIdx.x;

  float m1 = pm[(size_t)tid * 64 + b];
  float l1 = pl[(size_t)tid * 64 + b];
  int nb2 = tid + 256;
  if (nb2 < NBL) {
    float m2 = pm[(size_t)nb2 * 64 + b];
    float l2 = pl[(size_t)nb2 * 64 + b];
    float M = fmaxf(m1, m2);
    l1 = l1 * __expf(m1 - M) + l2 * __expf(m2 - M);
    m1 = M;
  }
  rm[tid] = m1; rl[tid] = l1;
  __syncthreads();
  for (int off = 128; off > 0; off >>= 1) {
    if (tid < off) {
      float ma = rm[tid], mb = rm[tid + off];
      float M = fmaxf(ma, mb);
      rl[tid] = rl[tid] * __expf(ma - M) + rl[tid + off] * __expf(mb - M);
      rm[tid] = M;
    }
    __syncthreads();
  }
  float logZ = rm[0] + __logf(rl[0]);
  size_t base = ((size_t)b * T + t) * V + (size_t)ch * 256;
  lp[base + tid] -= logZ;
}

// ============================ host launcher ================================
static void run_legacy(void* const* d_in, void* d_out, void* d_ws, size_t ws_size,
                       hipStream_t stream)
{
  const float* enc  = (const float*)d_in[0];
  const float* eh   = (const float*)d_in[1];
  const float* ec   = (const float*)d_in[2];
  const int*   tok  = (const int*)d_in[4];
  const float* emb  = (const float*)d_in[5];
  const float* W1   = (const float*)d_in[6];
  const float* b1   = (const float*)d_in[7];
  const float* W2   = (const float*)d_in[8];
  const float* b2   = (const float*)d_in[9];
  const float* Vw   = (const float*)d_in[10];
  const float* Vb   = (const float*)d_in[11];
  const float* W_ih = (const float*)d_in[12];
  const float* W_hh = (const float*)d_in[13];
  const float* b_ih = (const float*)d_in[14];
  const float* b_hh = (const float*)d_in[15];
  const float* outW = (const float*)d_in[16];
  const float* outb = (const float*)d_in[17];
  const float* br1W = (const float*)d_in[18];
  const float* br1b = (const float*)d_in[19];
  const float* br2W = (const float*)d_in[20];
  const float* br2b = (const float*)d_in[21];

  float* out    = (float*)d_out;
  float* out_h  = out + (size_t)B * T * V;
  float* out_c  = out_h + BH;
  float* out_at = out_c + BH;

  char* wp = (char*)d_ws;
  auto alloc = [&](size_t bytes) {
    char* p = wp; wp += (bytes + 255) & ~(size_t)255; return p;
  };
  float* keysL   = (float*)alloc((size_t)S * H * 4);
  float* hbuf0   = (float*)alloc((size_t)BH * 4);
  float* hbuf1   = (float*)alloc((size_t)BH * 4);
  float* cbuf0L  = (float*)alloc((size_t)BH * 4);
  float* cbuf1L  = (float*)alloc((size_t)BH * 4);
  float* qW1vL   = (float*)alloc((size_t)BH * 4);
  float* scoresL = (float*)alloc((size_t)B * S * 4);
  float* xbuf    = (float*)alloc((size_t)B * KX * 4);
  float* gates   = (float*)alloc((size_t)B * H4 * 4);
  float* pmvL    = (float*)alloc((size_t)NBL * 64 * 4);
  float* plvL    = (float*)alloc((size_t)NBL * 64 * 4);
  unsigned short* outWbL = (unsigned short*)alloc((size_t)V * H * 2);
  size_t need_out = (size_t)(wp - (char*)d_ws);
  unsigned short* wihbL = (unsigned short*)alloc((size_t)H4 * 2 * H * 2);
  unsigned short* whhbL = (unsigned short*)alloc((size_t)H4 * H * 2);
  unsigned short* w1bL  = (unsigned short*)alloc((size_t)H * H * 2);
  size_t need_all = (size_t)(wp - (char*)d_ws);

  const bool cvtOut = ws_size >= need_out;
  const bool cvtAll = ws_size >= need_all;

  if (cvtOut) k_f32_to_bf16<<<4096, 256, 0, stream>>>(outW, outWbL, V * H);
  if (cvtAll) {
    k_f32_to_bf16<<<2048, 256, 0, stream>>>(W_ih, wihbL, H4 * 2 * H);
    k_f32_to_bf16<<<1024, 256, 0, stream>>>(W_hh, whhbL, H4 * H);
    k_f32_to_bf16<<<256, 256, 0, stream>>>(W1, w1bL, H * H);
  }

  gemm64_mfma<<<16, 256, 0, stream>>>(enc,          H, W2, H, W2, H, H, b2, nullptr, keysL,          H, H, 0, nullptr, nullptr);
  gemm64_mfma<<<16, 256, 0, stream>>>(enc + 64 * H, H, W2, H, W2, H, H, b2, nullptr, keysL + 64 * H, H, H, 0, nullptr, nullptr);
  gemm64_mfma<<<16, 256, 0, stream>>>(eh, H, br1W, H, br1W, H, H, br1b, nullptr, hbuf0, H, H, 0, nullptr, nullptr);
  gemm64_mfma<<<16, 256, 0, stream>>>(ec, H, br2W, H, br2W, H, H, br2b, nullptr, cbuf0L, H, H, 0, nullptr, nullptr);

  float* hb[2] = {hbuf0, hbuf1};
  float* cb[2] = {cbuf0L, cbuf1L};

  for (int t = 0; t < T; ++t) {
    const int cur = t & 1, nxt = cur ^ 1;
    if (cvtAll)
      gemm64_mfma<<<16, 256, 0, stream>>>(hb[cur], H, w1bL, H, w1bL, H, H, b1, nullptr, qW1vL, H, H, 1, nullptr, nullptr);
    else
      gemm64_mfma<<<16, 256, 0, stream>>>(hb[cur], H, W1, H, W1, H, H, b1, nullptr, qW1vL, H, H, 0, nullptr, nullptr);
    k_scores_leg<<<256, 256, 0, stream>>>(qW1vL, keysL, Vw, Vb, scoresL);
    k_attn_ctx_leg<<<256, 256, 0, stream>>>(scoresL, enc, emb, tok, hb[cur], xbuf, out_at, t);
    if (cvtAll)
      gemm64_mfma<<<64, 256, 0, stream>>>(xbuf, KX, wihbL, 2 * H, whhbL, H, 2 * H, b_ih, b_hh, gates, H4, KX, 1, nullptr, nullptr);
    else
      gemm64_mfma<<<64, 256, 0, stream>>>(xbuf, KX, W_ih, 2 * H, W_hh, H, 2 * H, b_ih, b_hh, gates, H4, KX, 0, nullptr, nullptr);
    k_cell_leg<<<256, 256, 0, stream>>>(gates, cb[cur], hb[nxt], cb[nxt], out_h, out_c, t == T - 1);
    if (cvtOut)
      gemm64_mfma<<<NBL, 256, 0, stream>>>(hb[nxt], H, outWbL, H, outWbL, H, H, outb, nullptr, out + (size_t)t * V, (size_t)T * V, H, 1, pmvL, plvL);
    else
      gemm64_mfma<<<NBL, 256, 0, stream>>>(hb[nxt], H, outW, H, outW, H, H, outb, nullptr, out + (size_t)t * V, (size_t)T * V, H, 0, pmvL, plvL);
    k_norm_leg<<<64 * 125, 256, 0, stream>>>(pmvL, plvL, out, t);
  }
}

extern "C" void kernel_launch(void* const* d_in, const int* in_sizes, int n_in,
                              void* d_out, int out_size, void* d_ws, size_t ws_size,
                              hipStream_t stream)
{
  (void)in_sizes; (void)n_in; (void)out_size;
  const float* enc  = (const float*)d_in[0];
  const float* eh   = (const float*)d_in[1];
  const float* ec   = (const float*)d_in[2];
  const int*   tok  = (const int*)d_in[4];
  const float* emb  = (const float*)d_in[5];
  const float* W1   = (const float*)d_in[6];
  const float* b1   = (const float*)d_in[7];
  const float* W2   = (const float*)d_in[8];
  const float* b2   = (const float*)d_in[9];
  const float* Vw   = (const float*)d_in[10];
  const float* Vb   = (const float*)d_in[11];
  const float* W_ih = (const float*)d_in[12];
  const float* W_hh = (const float*)d_in[13];
  const float* b_ih = (const float*)d_in[14];
  const float* b_hh = (const float*)d_in[15];
  const float* outW = (const float*)d_in[16];
  const float* outb = (const float*)d_in[17];
  const float* br1W = (const float*)d_in[18];
  const float* br1b = (const float*)d_in[19];
  const float* br2W = (const float*)d_in[20];
  const float* br2b = (const float*)d_in[21];

  float* out    = (float*)d_out;
  float* out_lp = out;
  float* out_h  = out + (size_t)B * T * V;
  float* out_c  = out_h + BH;
  float* out_at = out_c + BH;

  char* wp = (char*)d_ws;
  auto alloc = [&](size_t bytes) {
    char* p = wp; wp += (bytes + 255) & ~(size_t)255; return p;
  };
  float* keys   = (float*)alloc((size_t)S * H * 4);
  float* cbuf0  = (float*)alloc((size_t)BH * 4);
  float* cbuf1  = (float*)alloc((size_t)BH * 4);
  float* qW1p   = (float*)alloc((size_t)4 * BH * 4);
  unsigned short* xbufb = (unsigned short*)alloc((size_t)B * KX * 2);
  float* gpart  = (float*)alloc((size_t)6 * B * H4 * 4);
  float* pmv    = (float*)alloc((size_t)NBL * 32 * 64 * 4);   // [nt*32+mt][64]
  float* plv    = (float*)alloc((size_t)NBL * 32 * 64 * 4);
  float* logZ2  = (float*)alloc((size_t)T * B * 4);
  unsigned short* hhistb = (unsigned short*)alloc((size_t)(T + 1) * BH * 2);
  float*          hhistf = (float*)alloc((size_t)(T + 1) * BH * 4);
  unsigned short* w1b  = (unsigned short*)alloc((size_t)H * H * 2);
  unsigned short* wihb = (unsigned short*)alloc((size_t)H4 * 2 * H * 2);
  unsigned short* whhb = (unsigned short*)alloc((size_t)H4 * H * 2);
  size_t need_mid = (size_t)(wp - (char*)d_ws);
  unsigned short* outWb = (unsigned short*)alloc((size_t)V * H * 2);
  size_t need_full = (size_t)(wp - (char*)d_ws);

  if (ws_size < need_mid) {
    run_legacy(d_in, d_out, d_ws, ws_size, stream);
    return;
  }
  const bool full = ws_size >= need_full;

  // ---- prep: weight converts + keys/bridge GEMMs ----
  k_f32_to_bf16<<<2048, 256, 0, stream>>>(W_ih, wihb, H4 * 2 * H);
  k_f32_to_bf16<<<1024, 256, 0, stream>>>(W_hh, whhb, H4 * H);
  k_f32_to_bf16<<<256, 256, 0, stream>>>(W1, w1b, H * H);
  if (full) k_f32_to_bf16<<<4096, 256, 0, stream>>>(outW, outWb, V * H);

  gemm64_mfma<<<16, 256, 0, stream>>>(enc,          H, W2, H, W2, H, H, b2, nullptr, keys,          H, H, 0, nullptr, nullptr);
  gemm64_mfma<<<16, 256, 0, stream>>>(enc + 64 * H, H, W2, H, W2, H, H, b2, nullptr, keys + 64 * H, H, H, 0, nullptr, nullptr);
  gemm64_mfma<<<16, 256, 0, stream>>>(eh, H, br1W, H, br1W, H, H, br1b, nullptr, hhistf, H, H, 0, nullptr, nullptr);  // h0 -> slot 0
  gemm64_mfma<<<16, 256, 0, stream>>>(ec, H, br2W, H, br2W, H, H, br2b, nullptr, cbuf0, H, H, 0, nullptr, nullptr);
  k_f32_to_bf16<<<32, 256, 0, stream>>>(hhistf, hhistb, BH);   // slot 0 bf16

  float* cb[2] = {cbuf0, cbuf1};

  // ---- 32 recurrence steps: 4 small launches each ----
  for (int t = 0; t < T; ++t) {
    const unsigned short* hbt = hhistb + (size_t)t * BH;
    k_qw1x<<<64, 256, 0, stream>>>(hbt, w1b, qW1p);
    k_attn2<<<256, 256, 0, stream>>>(qW1p, b1, keys, Vw, Vb, enc, emb, tok,
                                     hbt, xbufb, out_at, t);
    k_gates2<<<384, 256, 0, stream>>>(xbufb, wihb, whhb, gpart);
    k_cell2<<<256, 256, 0, stream>>>(gpart, b_ih, b_hh, cb[t & 1], cb[(t & 1) ^ 1],
                                     hhistb + (size_t)(t + 1) * BH,
                                     hhistf + (size_t)(t + 1) * BH,
                                     out_h, out_c, t == T - 1);
  }

  // ---- finale: one batched logits GEMM + logZ + normalize ----
  if (full)
    k_biglogits_fast<<<NBL * 32, 256, 0, stream>>>(hhistb + BH, outWb, outb,
                                                   out_lp, pmv, plv);
  else
    k_biglogits_leg<<<NBL * 32, 256, 0, stream>>>(hhistf + BH, outW, outb,
                                                  out_lp, pmv, plv);
  k_logz2<<<T * B, 256, 0, stream>>>(pmv, plv, logZ2);
  k_norm2<<<16000, 256, 0, stream>>>(out_lp, logZ2);
}